// Round 1
// baseline (5300.578 us; speedup 1.0000x reference)
//
#include <hip/hip_runtime.h>
#include <cmath>

#define BATCH 2
#define LSEQ 2048
#define DMODEL 1024
#define DINNER 2048
#define NHEADS 32
#define DHEAD 64
#define DSTATE 64
#define DCONV 4
#define CONVDIM (DINNER + 2*DSTATE)            // 2176
#define DINPROJ (2*DINNER + 2*DSTATE + NHEADS) // 4256
#define CHUNKSZ 256
#define NCHUNK (LSEQ/CHUNKSZ)                  // 8
#define MROWS (BATCH*LSEQ)                     // 4096
#define EPSF 1e-5f

// ---------------- reductions ----------------
__device__ __forceinline__ float block_reduce_sum_256(float v, float* sb) {
  for (int off = 32; off > 0; off >>= 1) v += __shfl_down(v, off, 64);
  int lane = threadIdx.x & 63, wid = threadIdx.x >> 6;
  if (lane == 0) sb[wid] = v;
  __syncthreads();
  return sb[0] + sb[1] + sb[2] + sb[3];
}

// ---------------- K1: rmsnorm (width 1024) ----------------
__global__ __launch_bounds__(256) void rmsnorm_k(const float* __restrict__ x,
                                                 const float* __restrict__ w,
                                                 float* __restrict__ out) {
  __shared__ float sb[4];
  int r = blockIdx.x;
  const float* xr = x + (size_t)r * DMODEL;
  float* orow = out + (size_t)r * DMODEL;
  float v[4]; float ssq = 0.f;
  for (int i = 0; i < 4; i++) {
    v[i] = xr[threadIdx.x + i * 256];
    ssq += v[i] * v[i];
  }
  float s = block_reduce_sum_256(ssq, sb);
  float sc = rsqrtf(s / (float)DMODEL + EPSF);
  for (int i = 0; i < 4; i++) {
    int c = threadIdx.x + i * 256;
    orow[c] = v[i] * sc * w[c];
  }
}

// ---------------- K2/K10: fp32 NT GEMM  C[M,N] = A[M,K] * Bw[N,K]^T (+resid) ----------------
__global__ __launch_bounds__(256) void gemm_nt(const float* __restrict__ A,
                                               const float* __restrict__ Bw,
                                               float* __restrict__ C,
                                               const float* __restrict__ resid,
                                               int M, int N, int K) {
  __shared__ __align__(16) float As[16][68];
  __shared__ __align__(16) float Bs[16][68];
  int tid = threadIdx.x;
  int tx = tid & 15, ty = tid >> 4;
  int m0 = blockIdx.y * 64, n0 = blockIdx.x * 64;
  float acc[4][4] = {};
  for (int k0 = 0; k0 < K; k0 += 16) {
    for (int i = 0; i < 4; i++) {
      int lin = tid * 4 + i;
      int row = lin >> 4, kk = lin & 15;
      As[kk][row] = A[(size_t)(m0 + row) * K + k0 + kk];
      int n = n0 + row;
      Bs[kk][row] = (n < N) ? Bw[(size_t)n * K + k0 + kk] : 0.f;
    }
    __syncthreads();
    for (int kk = 0; kk < 16; kk++) {
      float4 a = reinterpret_cast<const float4*>(&As[kk][0])[ty];
      float4 b = reinterpret_cast<const float4*>(&Bs[kk][0])[tx];
      float av[4] = {a.x, a.y, a.z, a.w};
      float bv[4] = {b.x, b.y, b.z, b.w};
      for (int i = 0; i < 4; i++)
        for (int j = 0; j < 4; j++) acc[i][j] += av[i] * bv[j];
    }
    __syncthreads();
  }
  for (int i = 0; i < 4; i++) {
    int m = m0 + ty * 4 + i;
    for (int j = 0; j < 4; j++) {
      int n = n0 + tx * 4 + j;
      if (n < N) {
        size_t idx = (size_t)m * N + n;
        float r = resid ? resid[idx] : 0.f;
        C[idx] = acc[i][j] + r;
      }
    }
  }
}

// ---------------- K3: depthwise conv + silu ----------------
__global__ __launch_bounds__(256) void conv_silu_k(const float* __restrict__ zx,
                                                   const float* __restrict__ cw,
                                                   const float* __restrict__ cb,
                                                   float* __restrict__ xBC) {
  int ch = blockIdx.x * 256 + threadIdx.x;
  if (ch >= CONVDIM) return;
  int r = blockIdx.y;
  int b = r >> 11, l = r & (LSEQ - 1);
  float acc = cb[ch];
  for (int k = 0; k < DCONV; k++) {
    int ls = l - (DCONV - 1) + k;
    if (ls >= 0)
      acc += zx[(size_t)(b * LSEQ + ls) * DINPROJ + DINNER + ch] * cw[ch * DCONV + k];
  }
  float s = acc / (1.f + expf(-acc));
  xBC[(size_t)r * CONVDIM + ch] = s;
}

// ---------------- K4: dt softplus ----------------
__global__ __launch_bounds__(256) void dt_k(const float* __restrict__ zx,
                                            const float* __restrict__ dt_bias,
                                            float* __restrict__ dt_sp) {
  int g = blockIdx.x * 256 + threadIdx.x;  // MROWS*32
  int r = g >> 5, h = g & 31;
  float v = zx[(size_t)r * DINPROJ + DINNER + CONVDIM + h] + dt_bias[h];
  dt_sp[g] = (v > 20.f) ? v : log1pf(expf(v));
}

// ---------------- K5: per-chunk inclusive cumsum of dt*A ----------------
__global__ __launch_bounds__(256) void cumsum_k(const float* __restrict__ dt_sp,
                                                const float* __restrict__ A_log,
                                                float* __restrict__ dtA_cs) {
  __shared__ float buf[256];
  int bid = blockIdx.x;  // ((b*8+c)*32+h)
  int h = bid & 31, c = (bid >> 5) & 7, b = bid >> 8;
  int l = threadIdx.x;
  float Aneg = -expf(A_log[h]);
  int row = b * LSEQ + c * CHUNKSZ + l;
  buf[l] = dt_sp[row * 32 + h] * Aneg;
  __syncthreads();
  for (int off = 1; off < 256; off <<= 1) {
    float add = (l >= off) ? buf[l - off] : 0.f;
    __syncthreads();
    buf[l] += add;
    __syncthreads();
  }
  dtA_cs[(size_t)bid * CHUNKSZ + l] = buf[l];
}

// ---------------- K6: per-chunk end states: S[p][n] = sum_l Xdt[l,p]*exp(T-cs[l])*B[l,n] ----------------
__global__ __launch_bounds__(256) void states_k(const float* __restrict__ xBC,
                                                const float* __restrict__ dt_sp,
                                                const float* __restrict__ dtA_cs,
                                                float* __restrict__ st_raw) {
  __shared__ __align__(16) float Bs[64][68];
  __shared__ __align__(16) float Xs[64][68];
  __shared__ float wrow[64];
  int bid = blockIdx.x;  // ((b*8+c)*32+h)
  int h = bid & 31, c = (bid >> 5) & 7, b = bid >> 8;
  int tid = threadIdx.x;
  int cbase = bid * CHUNKSZ;
  int rowbase = b * LSEQ + c * CHUNKSZ;
  float T = dtA_cs[cbase + CHUNKSZ - 1];
  float acc[16] = {};
  int n = tid & 63, pb = (tid >> 6) * 16;
  for (int lt = 0; lt < 4; lt++) {
    if (tid < 64) {
      int row = rowbase + lt * 64 + tid;
      wrow[tid] = dt_sp[row * 32 + h] * expf(T - dtA_cs[cbase + lt * 64 + tid]);
    }
    __syncthreads();
    for (int i = 0; i < 16; i++) {
      int idx = tid + i * 256;
      int l = idx >> 6, col = idx & 63;
      int row = rowbase + lt * 64 + l;
      Bs[l][col] = xBC[(size_t)row * CONVDIM + DINNER + col];
      Xs[l][col] = xBC[(size_t)row * CONVDIM + h * DHEAD + col] * wrow[l];
    }
    __syncthreads();
    for (int l = 0; l < 64; l++) {
      float bv = Bs[l][n];
      const float4* xp = reinterpret_cast<const float4*>(&Xs[l][0]);
      float4 x0 = xp[pb / 4 + 0], x1 = xp[pb / 4 + 1], x2 = xp[pb / 4 + 2], x3 = xp[pb / 4 + 3];
      acc[0] += x0.x * bv; acc[1] += x0.y * bv; acc[2] += x0.z * bv; acc[3] += x0.w * bv;
      acc[4] += x1.x * bv; acc[5] += x1.y * bv; acc[6] += x1.z * bv; acc[7] += x1.w * bv;
      acc[8] += x2.x * bv; acc[9] += x2.y * bv; acc[10] += x2.z * bv; acc[11] += x2.w * bv;
      acc[12] += x3.x * bv; acc[13] += x3.y * bv; acc[14] += x3.z * bv; acc[15] += x3.w * bv;
    }
    __syncthreads();
  }
  size_t base = (size_t)bid * (DHEAD * DSTATE);
  for (int j = 0; j < 16; j++) st_raw[base + (size_t)(pb + j) * 64 + n] = acc[j];
}

// ---------------- K7: inter-chunk scan ----------------
__global__ __launch_bounds__(256) void scan_k(const float* __restrict__ st_raw,
                                              const float* __restrict__ dtA_cs,
                                              float* __restrict__ st_in) {
  int bid = blockIdx.x;  // b*32+h
  int h = bid & 31, b = bid >> 5;
  int tid = threadIdx.x;
  float s[16];
  for (int i = 0; i < 16; i++) s[i] = 0.f;
  for (int c = 0; c < NCHUNK; c++) {
    int g = (b * NCHUNK + c) * 32 + h;
    float dec = expf(dtA_cs[(size_t)g * CHUNKSZ + CHUNKSZ - 1]);
    size_t base = (size_t)g * (DHEAD * DSTATE);
    for (int i = 0; i < 16; i++) {
      int idx = tid + i * 256;
      st_in[base + idx] = s[i];
      s[i] = s[i] * dec + st_raw[base + idx];
    }
  }
}

// ---------------- K8: Y = (masked scores)@Xdt + exp(cs)*C@state^T + D*X ----------------
__global__ __launch_bounds__(256) void ydiag_k(const float* __restrict__ xBC,
                                               const float* __restrict__ dt_sp,
                                               const float* __restrict__ dtA_cs,
                                               const float* __restrict__ st_in,
                                               const float* __restrict__ Dvec,
                                               float* __restrict__ Y) {
  __shared__ __align__(16) float Cs[64][68];
  __shared__ __align__(16) float BX[64][68];
  __shared__ float Ss[64][65];
  __shared__ float cs_l[64], cs_s[64], ecs[64];
  int bid = blockIdx.x;
  int lt = bid & 3, h = (bid >> 2) & 31, c = (bid >> 7) & 7, b = bid >> 10;
  int tid = threadIdx.x;
  int g = (b * NCHUNK + c) * 32 + h;
  int cbase = g * CHUNKSZ;
  int rowbase = b * LSEQ + c * CHUNKSZ;
  int l0 = lt * 64;
  if (tid < 64) {
    float cv = dtA_cs[cbase + l0 + tid];
    cs_l[tid] = cv;
    ecs[tid] = expf(cv);
  }
  for (int i = 0; i < 16; i++) {
    int idx = tid + i * 256;
    int l = idx >> 6, nn = idx & 63;
    Cs[l][nn] = xBC[(size_t)(rowbase + l0 + l) * CONVDIM + DINNER + DSTATE + nn];
  }
  float acc[16] = {};
  int sl = tid & 63, lq = (tid >> 6) * 16;   // phase A: thread owns s-col sl, 16 l rows
  int lloc = tid & 63, pb = (tid >> 6) * 16; // phase B: thread owns l row lloc, 16 p cols
  for (int st = 0; st <= lt; st++) {
    int s0 = st * 64;
    if (tid < 64) cs_s[tid] = dtA_cs[cbase + s0 + tid];
    for (int i = 0; i < 16; i++) {
      int idx = tid + i * 256;
      int srow = idx >> 6, nn = idx & 63;
      BX[srow][nn] = xBC[(size_t)(rowbase + s0 + srow) * CONVDIM + DINNER + nn];
    }
    __syncthreads();
    // scores
    for (int i = 0; i < 16; i++) {
      int l = lq + i;
      float w = 0.f;
      if (s0 + sl <= l0 + l) {
        const float4* cp = reinterpret_cast<const float4*>(&Cs[l][0]);
        const float4* bp = reinterpret_cast<const float4*>(&BX[sl][0]);
        float dot = 0.f;
        for (int q = 0; q < 16; q++) {
          float4 cv = cp[q], bv = bp[q];
          dot += cv.x * bv.x + cv.y * bv.y + cv.z * bv.z + cv.w * bv.w;
        }
        w = dot * expf(cs_l[l] - cs_s[sl]);
      }
      Ss[l][sl] = w;
    }
    __syncthreads();
    // overwrite BX with Xdt tile
    for (int i = 0; i < 16; i++) {
      int idx = tid + i * 256;
      int srow = idx >> 6, pp = idx & 63;
      int row = rowbase + s0 + srow;
      BX[srow][pp] = xBC[(size_t)row * CONVDIM + h * DHEAD + pp] * dt_sp[row * 32 + h];
    }
    __syncthreads();
    for (int s = 0; s < 64; s++) {
      float sv = Ss[lloc][s];
      const float4* xp = reinterpret_cast<const float4*>(&BX[s][0]);
      float4 x0 = xp[pb / 4 + 0], x1 = xp[pb / 4 + 1], x2 = xp[pb / 4 + 2], x3 = xp[pb / 4 + 3];
      acc[0] += sv * x0.x; acc[1] += sv * x0.y; acc[2] += sv * x0.z; acc[3] += sv * x0.w;
      acc[4] += sv * x1.x; acc[5] += sv * x1.y; acc[6] += sv * x1.z; acc[7] += sv * x1.w;
      acc[8] += sv * x2.x; acc[9] += sv * x2.y; acc[10] += sv * x2.z; acc[11] += sv * x2.w;
      acc[12] += sv * x3.x; acc[13] += sv * x3.y; acc[14] += sv * x3.z; acc[15] += sv * x3.w;
    }
    __syncthreads();
  }
  // Y_off: load state^T into BX as sinT[n][p]
  for (int i = 0; i < 16; i++) {
    int idx = tid + i * 256;
    int p = idx >> 6, nn = idx & 63;
    BX[nn][p] = st_in[(size_t)g * (DHEAD * DSTATE) + p * 64 + nn];
  }
  __syncthreads();
  float offacc[16] = {};
  for (int nn = 0; nn < 64; nn++) {
    float cv = Cs[lloc][nn];
    const float4* sp = reinterpret_cast<const float4*>(&BX[nn][0]);
    float4 s0v = sp[pb / 4 + 0], s1v = sp[pb / 4 + 1], s2v = sp[pb / 4 + 2], s3v = sp[pb / 4 + 3];
    offacc[0] += cv * s0v.x; offacc[1] += cv * s0v.y; offacc[2] += cv * s0v.z; offacc[3] += cv * s0v.w;
    offacc[4] += cv * s1v.x; offacc[5] += cv * s1v.y; offacc[6] += cv * s1v.z; offacc[7] += cv * s1v.w;
    offacc[8] += cv * s2v.x; offacc[9] += cv * s2v.y; offacc[10] += cv * s2v.z; offacc[11] += cv * s2v.w;
    offacc[12] += cv * s3v.x; offacc[13] += cv * s3v.y; offacc[14] += cv * s3v.z; offacc[15] += cv * s3v.w;
  }
  float e = ecs[lloc];
  float Dh = Dvec[h];
  int grow = rowbase + l0 + lloc;
  for (int j = 0; j < 16; j++) {
    float xv = xBC[(size_t)grow * CONVDIM + h * DHEAD + pb + j];
    Y[(size_t)grow * DINNER + h * DHEAD + pb + j] = acc[j] + e * offacc[j] + Dh * xv;
  }
}

// ---------------- K9: gated rmsnorm over 2048 (in-place on Y) ----------------
__global__ __launch_bounds__(256) void gatenorm_k(float* __restrict__ Y,
                                                  const float* __restrict__ zx,
                                                  const float* __restrict__ gw) {
  __shared__ float sb[4];
  int r = blockIdx.x;
  float* yr = Y + (size_t)r * DINNER;
  const float* zr = zx + (size_t)r * DINPROJ;
  float t[8]; float ssq = 0.f;
  for (int i = 0; i < 8; i++) {
    int cc = threadIdx.x + i * 256;
    float z = zr[cc];
    float gv = yr[cc] * (z / (1.f + expf(-z)));
    t[i] = gv;
    ssq += gv * gv;
  }
  float s = block_reduce_sum_256(ssq, sb);
  float sc = rsqrtf(s / (float)DINNER + EPSF);
  for (int i = 0; i < 8; i++) {
    int cc = threadIdx.x + i * 256;
    yr[cc] = t[i] * sc * gw[cc];
  }
}

// ---------------- launch ----------------
extern "C" void kernel_launch(void* const* d_in, const int* in_sizes, int n_in,
                              void* d_out, int out_size, void* d_ws, size_t ws_size,
                              hipStream_t stream) {
  const float* x_in     = (const float*)d_in[0];
  const float* in_w     = (const float*)d_in[1];
  const float* conv_w   = (const float*)d_in[2];
  const float* conv_b   = (const float*)d_in[3];
  const float* dt_bias  = (const float*)d_in[4];
  const float* A_log    = (const float*)d_in[5];
  const float* Dvec     = (const float*)d_in[6];
  const float* gnorm_w  = (const float*)d_in[7];
  const float* out_w    = (const float*)d_in[8];
  const float* rms_w    = (const float*)d_in[9];
  float* out = (float*)d_out;

  float* ws = (float*)d_ws;
  size_t o = 0;
  float* x_cur  = ws + o; o += (size_t)MROWS * DMODEL;
  float* xn     = ws + o; o += (size_t)MROWS * DMODEL;
  float* zx     = ws + o; o += (size_t)MROWS * DINPROJ;
  float* xBC    = ws + o; o += (size_t)MROWS * CONVDIM;
  float* dt_sp  = ws + o; o += (size_t)MROWS * NHEADS;
  float* dtA_cs = ws + o; o += (size_t)BATCH * NCHUNK * NHEADS * CHUNKSZ;
  float* st_raw = ws + o; o += (size_t)BATCH * NCHUNK * NHEADS * DHEAD * DSTATE;
  float* st_in  = ws + o; o += (size_t)BATCH * NCHUNK * NHEADS * DHEAD * DSTATE;
  float* Ybuf   = ws + o; o += (size_t)MROWS * DINNER;

  hipMemcpyAsync(x_cur, x_in, (size_t)MROWS * DMODEL * sizeof(float),
                 hipMemcpyDeviceToDevice, stream);

  for (int i = 0; i < 4; i++) {
    const float* in_w_i   = in_w    + (size_t)i * DINPROJ * DMODEL;
    const float* conv_w_i = conv_w  + (size_t)i * CONVDIM * DCONV;
    const float* conv_b_i = conv_b  + (size_t)i * CONVDIM;
    const float* dtb_i    = dt_bias + (size_t)i * NHEADS;
    const float* Alog_i   = A_log   + (size_t)i * NHEADS;
    const float* D_i      = Dvec    + (size_t)i * NHEADS;
    const float* gw_i     = gnorm_w + (size_t)i * DINNER;
    const float* out_w_i  = out_w   + (size_t)i * DMODEL * DINNER;
    const float* rms_w_i  = rms_w   + (size_t)i * DMODEL;

    rmsnorm_k<<<MROWS, 256, 0, stream>>>(x_cur, rms_w_i, xn);
    gemm_nt<<<dim3((DINPROJ + 63) / 64, MROWS / 64), 256, 0, stream>>>(
        xn, in_w_i, zx, nullptr, MROWS, DINPROJ, DMODEL);
    conv_silu_k<<<dim3((CONVDIM + 255) / 256, MROWS), 256, 0, stream>>>(
        zx, conv_w_i, conv_b_i, xBC);
    dt_k<<<MROWS * NHEADS / 256, 256, 0, stream>>>(zx, dtb_i, dt_sp);
    cumsum_k<<<BATCH * NCHUNK * NHEADS, 256, 0, stream>>>(dt_sp, Alog_i, dtA_cs);
    states_k<<<BATCH * NCHUNK * NHEADS, 256, 0, stream>>>(xBC, dt_sp, dtA_cs, st_raw);
    scan_k<<<BATCH * NHEADS, 256, 0, stream>>>(st_raw, dtA_cs, st_in);
    ydiag_k<<<BATCH * NCHUNK * NHEADS * 4, 256, 0, stream>>>(
        xBC, dt_sp, dtA_cs, st_in, D_i, Ybuf);
    gatenorm_k<<<MROWS, 256, 0, stream>>>(Ybuf, zx, gw_i);
    float* outC = (i == 3) ? out : x_cur;
    gemm_nt<<<dim3(DMODEL / 64, MROWS / 64), 256, 0, stream>>>(
        Ybuf, out_w_i, outC, x_cur, MROWS, DMODEL, DINNER);
  }
}

// Round 2
// 2246.013 us; speedup vs baseline: 2.3600x; 2.3600x over previous
//
#include <hip/hip_runtime.h>
#include <cmath>

#define BATCH 2
#define LSEQ 2048
#define DMODEL 1024
#define DINNER 2048
#define NHEADS 32
#define DHEAD 64
#define DSTATE 64
#define DCONV 4
#define CONVDIM (DINNER + 2*DSTATE)            // 2176
#define DINPROJ (2*DINNER + 2*DSTATE + NHEADS) // 4256
#define DINPROJ_PAD 4352                       // 34*128
#define CHUNKSZ 256
#define NCHUNK (LSEQ/CHUNKSZ)                  // 8
#define MROWS (BATCH*LSEQ)                     // 4096
#define EPSF 1e-5f

typedef __attribute__((ext_vector_type(8))) short shortx8;
typedef __attribute__((ext_vector_type(4))) float floatx4;

__device__ __forceinline__ ushort f2bf(float f) {
  unsigned u = __float_as_uint(f);
  unsigned r = (u + 0x7fffu + ((u >> 16) & 1u)) >> 16;
  return (ushort)r;
}

__device__ __forceinline__ void async_load16(const void* g, void* l) {
  __builtin_amdgcn_global_load_lds(
      (const __attribute__((address_space(1))) void*)g,
      (__attribute__((address_space(3))) void*)l, 16, 0, 0);
}

// ---------------- reductions ----------------
__device__ __forceinline__ float block_reduce_sum_256(float v, float* sb) {
  for (int off = 32; off > 0; off >>= 1) v += __shfl_down(v, off, 64);
  int lane = threadIdx.x & 63, wid = threadIdx.x >> 6;
  if (lane == 0) sb[wid] = v;
  __syncthreads();
  return sb[0] + sb[1] + sb[2] + sb[3];
}

// ---------------- fp32 -> bf16 (with zero tail padding) ----------------
__global__ __launch_bounds__(256) void cvt_bf16_k(const float* __restrict__ src,
                                                  ushort* __restrict__ dst,
                                                  size_t n_src, size_t n_dst) {
  size_t i = (size_t)blockIdx.x * 256 + threadIdx.x;
  if (i >= n_dst) return;
  float v = (i < n_src) ? src[i] : 0.f;
  dst[i] = f2bf(v);
}

// ---------------- K1: rmsnorm (width 1024) -> bf16 out ----------------
__global__ __launch_bounds__(256) void rmsnorm_k(const float* __restrict__ x,
                                                 const float* __restrict__ w,
                                                 ushort* __restrict__ out) {
  __shared__ float sb[4];
  int r = blockIdx.x;
  const float* xr = x + (size_t)r * DMODEL;
  ushort* orow = out + (size_t)r * DMODEL;
  float v[4]; float ssq = 0.f;
  for (int i = 0; i < 4; i++) {
    v[i] = xr[threadIdx.x + i * 256];
    ssq += v[i] * v[i];
  }
  float s = block_reduce_sum_256(ssq, sb);
  float sc = rsqrtf(s / (float)DMODEL + EPSF);
  for (int i = 0; i < 4; i++) {
    int c = threadIdx.x + i * 256;
    orow[c] = f2bf(v[i] * sc * w[c]);
  }
}

// ---------------- MFMA bf16 NT GEMM: C[M,N]f32 = A[M,K]bf16 * B[Npad,K]bf16^T (+resid) ----------------
// 128x128 tile, BK=64, 256 threads = 4 waves (2x2), each wave 4x4 of 16x16x32 MFMAs.
__global__ __launch_bounds__(256) void gemm_nt_mfma(const ushort* __restrict__ A,
                                                    const ushort* __restrict__ B,
                                                    float* __restrict__ C,
                                                    const float* __restrict__ resid,
                                                    int M, int N, int K) {
  __shared__ ushort Asm[128 * 64];  // 16 KB, row-major [row][k] contiguous
  __shared__ ushort Bsm[128 * 64];  // 16 KB
  int tid = threadIdx.x;
  int wid = tid >> 6, lane = tid & 63;
  int quad = lane >> 4, lrow = lane & 15;
  int m0 = blockIdx.y * 128, n0 = blockIdx.x * 128;
  int wm = (wid >> 1) * 64, wn = (wid & 1) * 64;
  floatx4 acc[4][4];
  for (int i = 0; i < 4; i++)
    for (int j = 0; j < 4; j++) acc[i][j] = (floatx4){0.f, 0.f, 0.f, 0.f};

  for (int k0 = 0; k0 < K; k0 += 64) {
    __syncthreads();
    // stage 16KB each of A,B: tile byte b = is*4096 + wid*1024 + lane*16
    for (int is = 0; is < 4; is++) {
      int boff = is * 4096 + wid * 1024;        // wave-uniform LDS base
      int b = boff + lane * 16;                 // per-lane byte within tile
      int row = b >> 7;                         // 128 B per row (64 bf16)
      int col = (b & 127) >> 1;                 // bf16 col
      async_load16(A + (size_t)(m0 + row) * K + k0 + col, (char*)Asm + boff);
      async_load16(B + (size_t)(n0 + row) * K + k0 + col, (char*)Bsm + boff);
    }
    __syncthreads();
    for (int kk = 0; kk < 64; kk += 32) {
      shortx8 af[4], bf[4];
      for (int i = 0; i < 4; i++)
        af[i] = *(const shortx8*)&Asm[(wm + i * 16 + lrow) * 64 + kk + quad * 8];
      for (int j = 0; j < 4; j++)
        bf[j] = *(const shortx8*)&Bsm[(wn + j * 16 + lrow) * 64 + kk + quad * 8];
      for (int i = 0; i < 4; i++)
        for (int j = 0; j < 4; j++)
          acc[i][j] = __builtin_amdgcn_mfma_f32_16x16x32_bf16(af[i], bf[j], acc[i][j], 0, 0, 0);
    }
  }
  bool hasR = (resid != nullptr);
  for (int i = 0; i < 4; i++) {
    int r0 = m0 + wm + i * 16 + quad * 4;
    for (int j = 0; j < 4; j++) {
      int n = n0 + wn + j * 16 + lrow;
      if (n < N) {
        for (int r = 0; r < 4; r++) {
          size_t idx = (size_t)(r0 + r) * N + n;
          float v = acc[i][j][r];
          if (hasR) v += resid[idx];
          C[idx] = v;
        }
      }
    }
  }
}

// ---------------- K3: depthwise conv + silu ----------------
__global__ __launch_bounds__(256) void conv_silu_k(const float* __restrict__ zx,
                                                   const float* __restrict__ cw,
                                                   const float* __restrict__ cb,
                                                   float* __restrict__ xBC) {
  int ch = blockIdx.x * 256 + threadIdx.x;
  if (ch >= CONVDIM) return;
  int r = blockIdx.y;
  int b = r >> 11, l = r & (LSEQ - 1);
  float acc = cb[ch];
  for (int k = 0; k < DCONV; k++) {
    int ls = l - (DCONV - 1) + k;
    if (ls >= 0)
      acc += zx[(size_t)(b * LSEQ + ls) * DINPROJ + DINNER + ch] * cw[ch * DCONV + k];
  }
  float s = acc / (1.f + expf(-acc));
  xBC[(size_t)r * CONVDIM + ch] = s;
}

// ---------------- K4: dt softplus ----------------
__global__ __launch_bounds__(256) void dt_k(const float* __restrict__ zx,
                                            const float* __restrict__ dt_bias,
                                            float* __restrict__ dt_sp) {
  int g = blockIdx.x * 256 + threadIdx.x;  // MROWS*32
  int r = g >> 5, h = g & 31;
  float v = zx[(size_t)r * DINPROJ + DINNER + CONVDIM + h] + dt_bias[h];
  dt_sp[g] = (v > 20.f) ? v : log1pf(expf(v));
}

// ---------------- K5: per-chunk inclusive cumsum of dt*A ----------------
__global__ __launch_bounds__(256) void cumsum_k(const float* __restrict__ dt_sp,
                                                const float* __restrict__ A_log,
                                                float* __restrict__ dtA_cs) {
  __shared__ float buf[256];
  int bid = blockIdx.x;  // ((b*8+c)*32+h)
  int h = bid & 31, c = (bid >> 5) & 7, b = bid >> 8;
  int l = threadIdx.x;
  float Aneg = -expf(A_log[h]);
  int row = b * LSEQ + c * CHUNKSZ + l;
  buf[l] = dt_sp[row * 32 + h] * Aneg;
  __syncthreads();
  for (int off = 1; off < 256; off <<= 1) {
    float add = (l >= off) ? buf[l - off] : 0.f;
    __syncthreads();
    buf[l] += add;
    __syncthreads();
  }
  dtA_cs[(size_t)bid * CHUNKSZ + l] = buf[l];
}

// ---------------- K6: per-chunk end states ----------------
__global__ __launch_bounds__(256) void states_k(const float* __restrict__ xBC,
                                                const float* __restrict__ dt_sp,
                                                const float* __restrict__ dtA_cs,
                                                float* __restrict__ st_raw) {
  __shared__ __align__(16) float Bs[64][68];
  __shared__ __align__(16) float Xs[64][68];
  __shared__ float wrow[64];
  int bid = blockIdx.x;  // ((b*8+c)*32+h)
  int h = bid & 31, c = (bid >> 5) & 7, b = bid >> 8;
  int tid = threadIdx.x;
  int cbase = bid * CHUNKSZ;
  int rowbase = b * LSEQ + c * CHUNKSZ;
  float T = dtA_cs[cbase + CHUNKSZ - 1];
  float acc[16] = {};
  int n = tid & 63, pb = (tid >> 6) * 16;
  for (int lt = 0; lt < 4; lt++) {
    if (tid < 64) {
      int row = rowbase + lt * 64 + tid;
      wrow[tid] = dt_sp[row * 32 + h] * expf(T - dtA_cs[cbase + lt * 64 + tid]);
    }
    __syncthreads();
    for (int i = 0; i < 16; i++) {
      int idx = tid + i * 256;
      int l = idx >> 6, col = idx & 63;
      int row = rowbase + lt * 64 + l;
      Bs[l][col] = xBC[(size_t)row * CONVDIM + DINNER + col];
      Xs[l][col] = xBC[(size_t)row * CONVDIM + h * DHEAD + col] * wrow[l];
    }
    __syncthreads();
    for (int l = 0; l < 64; l++) {
      float bv = Bs[l][n];
      const float4* xp = reinterpret_cast<const float4*>(&Xs[l][0]);
      float4 x0 = xp[pb / 4 + 0], x1 = xp[pb / 4 + 1], x2 = xp[pb / 4 + 2], x3 = xp[pb / 4 + 3];
      acc[0] += x0.x * bv; acc[1] += x0.y * bv; acc[2] += x0.z * bv; acc[3] += x0.w * bv;
      acc[4] += x1.x * bv; acc[5] += x1.y * bv; acc[6] += x1.z * bv; acc[7] += x1.w * bv;
      acc[8] += x2.x * bv; acc[9] += x2.y * bv; acc[10] += x2.z * bv; acc[11] += x2.w * bv;
      acc[12] += x3.x * bv; acc[13] += x3.y * bv; acc[14] += x3.z * bv; acc[15] += x3.w * bv;
    }
    __syncthreads();
  }
  size_t base = (size_t)bid * (DHEAD * DSTATE);
  for (int j = 0; j < 16; j++) st_raw[base + (size_t)(pb + j) * 64 + n] = acc[j];
}

// ---------------- K7: inter-chunk scan (in-place: raw -> incoming state) ----------------
__global__ __launch_bounds__(256) void scan_k(float* __restrict__ st,
                                              const float* __restrict__ dtA_cs) {
  int bid = blockIdx.x;  // b*32+h
  int h = bid & 31, b = bid >> 5;
  int tid = threadIdx.x;
  float s[16];
  for (int i = 0; i < 16; i++) s[i] = 0.f;
  for (int c = 0; c < NCHUNK; c++) {
    int g = (b * NCHUNK + c) * 32 + h;
    float dec = expf(dtA_cs[(size_t)g * CHUNKSZ + CHUNKSZ - 1]);
    size_t base = (size_t)g * (DHEAD * DSTATE);
    for (int i = 0; i < 16; i++) {
      int idx = tid + i * 256;
      float raw = st[base + idx];
      st[base + idx] = s[i];
      s[i] = s[i] * dec + raw;
    }
  }
}

// ---------------- K8: Y = (masked scores)@Xdt + exp(cs)*C@state^T + D*X ----------------
__global__ __launch_bounds__(256) void ydiag_k(const float* __restrict__ xBC,
                                               const float* __restrict__ dt_sp,
                                               const float* __restrict__ dtA_cs,
                                               const float* __restrict__ st_in,
                                               const float* __restrict__ Dvec,
                                               float* __restrict__ Y) {
  __shared__ __align__(16) float Cs[64][68];
  __shared__ __align__(16) float BX[64][68];
  __shared__ float Ss[64][65];
  __shared__ float cs_l[64], cs_s[64], ecs[64];
  int bid = blockIdx.x;
  int lt = bid & 3, h = (bid >> 2) & 31, c = (bid >> 7) & 7, b = bid >> 10;
  int tid = threadIdx.x;
  int g = (b * NCHUNK + c) * 32 + h;
  int cbase = g * CHUNKSZ;
  int rowbase = b * LSEQ + c * CHUNKSZ;
  int l0 = lt * 64;
  if (tid < 64) {
    float cv = dtA_cs[cbase + l0 + tid];
    cs_l[tid] = cv;
    ecs[tid] = expf(cv);
  }
  for (int i = 0; i < 16; i++) {
    int idx = tid + i * 256;
    int l = idx >> 6, nn = idx & 63;
    Cs[l][nn] = xBC[(size_t)(rowbase + l0 + l) * CONVDIM + DINNER + DSTATE + nn];
  }
  float acc[16] = {};
  int sl = tid & 63, lq = (tid >> 6) * 16;
  int lloc = tid & 63, pb = (tid >> 6) * 16;
  for (int st = 0; st <= lt; st++) {
    int s0 = st * 64;
    if (tid < 64) cs_s[tid] = dtA_cs[cbase + s0 + tid];
    for (int i = 0; i < 16; i++) {
      int idx = tid + i * 256;
      int srow = idx >> 6, nn = idx & 63;
      BX[srow][nn] = xBC[(size_t)(rowbase + s0 + srow) * CONVDIM + DINNER + nn];
    }
    __syncthreads();
    for (int i = 0; i < 16; i++) {
      int l = lq + i;
      float w = 0.f;
      if (s0 + sl <= l0 + l) {
        const float4* cp = reinterpret_cast<const float4*>(&Cs[l][0]);
        const float4* bp = reinterpret_cast<const float4*>(&BX[sl][0]);
        float dot = 0.f;
        for (int q = 0; q < 16; q++) {
          float4 cv = cp[q], bv = bp[q];
          dot += cv.x * bv.x + cv.y * bv.y + cv.z * bv.z + cv.w * bv.w;
        }
        w = dot * expf(cs_l[l] - cs_s[sl]);
      }
      Ss[l][sl] = w;
    }
    __syncthreads();
    for (int i = 0; i < 16; i++) {
      int idx = tid + i * 256;
      int srow = idx >> 6, pp = idx & 63;
      int row = rowbase + s0 + srow;
      BX[srow][pp] = xBC[(size_t)row * CONVDIM + h * DHEAD + pp] * dt_sp[row * 32 + h];
    }
    __syncthreads();
    for (int s = 0; s < 64; s++) {
      float sv = Ss[lloc][s];
      const float4* xp = reinterpret_cast<const float4*>(&BX[s][0]);
      float4 x0 = xp[pb / 4 + 0], x1 = xp[pb / 4 + 1], x2 = xp[pb / 4 + 2], x3 = xp[pb / 4 + 3];
      acc[0] += sv * x0.x; acc[1] += sv * x0.y; acc[2] += sv * x0.z; acc[3] += sv * x0.w;
      acc[4] += sv * x1.x; acc[5] += sv * x1.y; acc[6] += sv * x1.z; acc[7] += sv * x1.w;
      acc[8] += sv * x2.x; acc[9] += sv * x2.y; acc[10] += sv * x2.z; acc[11] += sv * x2.w;
      acc[12] += sv * x3.x; acc[13] += sv * x3.y; acc[14] += sv * x3.z; acc[15] += sv * x3.w;
    }
    __syncthreads();
  }
  for (int i = 0; i < 16; i++) {
    int idx = tid + i * 256;
    int p = idx >> 6, nn = idx & 63;
    BX[nn][p] = st_in[(size_t)g * (DHEAD * DSTATE) + p * 64 + nn];
  }
  __syncthreads();
  float offacc[16] = {};
  for (int nn = 0; nn < 64; nn++) {
    float cv = Cs[lloc][nn];
    const float4* sp = reinterpret_cast<const float4*>(&BX[nn][0]);
    float4 s0v = sp[pb / 4 + 0], s1v = sp[pb / 4 + 1], s2v = sp[pb / 4 + 2], s3v = sp[pb / 4 + 3];
    offacc[0] += cv * s0v.x; offacc[1] += cv * s0v.y; offacc[2] += cv * s0v.z; offacc[3] += cv * s0v.w;
    offacc[4] += cv * s1v.x; offacc[5] += cv * s1v.y; offacc[6] += cv * s1v.z; offacc[7] += cv * s1v.w;
    offacc[8] += cv * s2v.x; offacc[9] += cv * s2v.y; offacc[10] += cv * s2v.z; offacc[11] += cv * s2v.w;
    offacc[12] += cv * s3v.x; offacc[13] += cv * s3v.y; offacc[14] += cv * s3v.z; offacc[15] += cv * s3v.w;
  }
  float e = ecs[lloc];
  float Dh = Dvec[h];
  int grow = rowbase + l0 + lloc;
  for (int j = 0; j < 16; j++) {
    float xv = xBC[(size_t)grow * CONVDIM + h * DHEAD + pb + j];
    Y[(size_t)grow * DINNER + h * DHEAD + pb + j] = acc[j] + e * offacc[j] + Dh * xv;
  }
}

// ---------------- K9: gated rmsnorm over 2048 -> bf16 out ----------------
__global__ __launch_bounds__(256) void gatenorm_k(const float* __restrict__ Y,
                                                  const float* __restrict__ zx,
                                                  const float* __restrict__ gw,
                                                  ushort* __restrict__ ybf) {
  __shared__ float sb[4];
  int r = blockIdx.x;
  const float* yr = Y + (size_t)r * DINNER;
  const float* zr = zx + (size_t)r * DINPROJ;
  ushort* orow = ybf + (size_t)r * DINNER;
  float t[8]; float ssq = 0.f;
  for (int i = 0; i < 8; i++) {
    int cc = threadIdx.x + i * 256;
    float z = zr[cc];
    float gv = yr[cc] * (z / (1.f + expf(-z)));
    t[i] = gv;
    ssq += gv * gv;
  }
  float s = block_reduce_sum_256(ssq, sb);
  float sc = rsqrtf(s / (float)DINNER + EPSF);
  for (int i = 0; i < 8; i++) {
    int cc = threadIdx.x + i * 256;
    orow[cc] = f2bf(t[i] * sc * gw[cc]);
  }
}

// ---------------- launch ----------------
extern "C" void kernel_launch(void* const* d_in, const int* in_sizes, int n_in,
                              void* d_out, int out_size, void* d_ws, size_t ws_size,
                              hipStream_t stream) {
  const float* x_in     = (const float*)d_in[0];
  const float* in_w     = (const float*)d_in[1];
  const float* conv_w   = (const float*)d_in[2];
  const float* conv_b   = (const float*)d_in[3];
  const float* dt_bias  = (const float*)d_in[4];
  const float* A_log    = (const float*)d_in[5];
  const float* Dvec     = (const float*)d_in[6];
  const float* gnorm_w  = (const float*)d_in[7];
  const float* out_w    = (const float*)d_in[8];
  const float* rms_w    = (const float*)d_in[9];
  float* out = (float*)d_out;

  float* ws = (float*)d_ws;
  size_t o = 0;
  float* x_cur  = ws + o; o += (size_t)MROWS * DMODEL;                 // 16.8 MB
  float* zx     = ws + o; o += (size_t)MROWS * DINPROJ;                // 69.7 MB
  float* xBC    = ws + o; o += (size_t)MROWS * CONVDIM;                // 35.7 MB
  float* dt_sp  = ws + o; o += (size_t)MROWS * NHEADS;                 // 0.5 MB
  float* dtA_cs = ws + o; o += (size_t)BATCH * NCHUNK * NHEADS * CHUNKSZ;         // 0.5 MB
  float* st     = ws + o; o += (size_t)BATCH * NCHUNK * NHEADS * DHEAD * DSTATE;  // 8.4 MB
  float* Ybuf   = ws + o; o += (size_t)MROWS * DINNER;                 // 33.6 MB
  ushort* act_bf = (ushort*)(ws + o); o += (size_t)MROWS * DINNER / 2; // 16.8 MB (xn_bf & y_bf share)
  ushort* w_bf   = (ushort*)(ws + o); o += (size_t)DINPROJ_PAD * DMODEL / 2; // 8.9 MB (in/out wt share)

  hipMemcpyAsync(x_cur, x_in, (size_t)MROWS * DMODEL * sizeof(float),
                 hipMemcpyDeviceToDevice, stream);

  for (int i = 0; i < 4; i++) {
    const float* in_w_i   = in_w    + (size_t)i * DINPROJ * DMODEL;
    const float* conv_w_i = conv_w  + (size_t)i * CONVDIM * DCONV;
    const float* conv_b_i = conv_b  + (size_t)i * CONVDIM;
    const float* dtb_i    = dt_bias + (size_t)i * NHEADS;
    const float* Alog_i   = A_log   + (size_t)i * NHEADS;
    const float* D_i      = Dvec    + (size_t)i * NHEADS;
    const float* gw_i     = gnorm_w + (size_t)i * DINNER;
    const float* out_w_i  = out_w   + (size_t)i * DMODEL * DINNER;
    const float* rms_w_i  = rms_w   + (size_t)i * DMODEL;

    // in_proj weights -> bf16, padded to 4352 rows
    {
      size_t ns = (size_t)DINPROJ * DMODEL, nd = (size_t)DINPROJ_PAD * DMODEL;
      cvt_bf16_k<<<(nd + 255) / 256, 256, 0, stream>>>(in_w_i, w_bf, ns, nd);
    }
    rmsnorm_k<<<MROWS, 256, 0, stream>>>(x_cur, rms_w_i, act_bf);
    gemm_nt_mfma<<<dim3(DINPROJ_PAD / 128, MROWS / 128), 256, 0, stream>>>(
        act_bf, w_bf, zx, nullptr, MROWS, DINPROJ, DMODEL);
    conv_silu_k<<<dim3((CONVDIM + 255) / 256, MROWS), 256, 0, stream>>>(
        zx, conv_w_i, conv_b_i, xBC);
    dt_k<<<MROWS * NHEADS / 256, 256, 0, stream>>>(zx, dtb_i, dt_sp);
    cumsum_k<<<BATCH * NCHUNK * NHEADS, 256, 0, stream>>>(dt_sp, Alog_i, dtA_cs);
    states_k<<<BATCH * NCHUNK * NHEADS, 256, 0, stream>>>(xBC, dt_sp, dtA_cs, st);
    scan_k<<<BATCH * NHEADS, 256, 0, stream>>>(st, dtA_cs);
    ydiag_k<<<BATCH * NCHUNK * NHEADS * 4, 256, 0, stream>>>(
        xBC, dt_sp, dtA_cs, st, D_i, Ybuf);
    gatenorm_k<<<MROWS, 256, 0, stream>>>(Ybuf, zx, gw_i, act_bf);
    // out_proj weights -> bf16 (1024x2048, no pad needed)
    {
      size_t ns = (size_t)DMODEL * DINNER;
      cvt_bf16_k<<<(ns + 255) / 256, 256, 0, stream>>>(out_w_i, w_bf, ns, ns);
    }
    float* outC = (i == 3) ? out : x_cur;
    gemm_nt_mfma<<<dim3(DMODEL / 128, MROWS / 128), 256, 0, stream>>>(
        act_bf, w_bf, outC, x_cur, MROWS, DMODEL, DINNER);
  }
}

// Round 3
// 1372.461 us; speedup vs baseline: 3.8621x; 1.6365x over previous
//
#include <hip/hip_runtime.h>
#include <cmath>

#define BATCH 2
#define LSEQ 2048
#define DMODEL 1024
#define DINNER 2048
#define NHEADS 32
#define DHEAD 64
#define DSTATE 64
#define DCONV 4
#define CONVDIM (DINNER + 2*DSTATE)            // 2176
#define DINPROJ (2*DINNER + 2*DSTATE + NHEADS) // 4256
#define DINPROJ_PAD 4352                       // 34*128
#define CHUNKSZ 256
#define NCHUNK (LSEQ/CHUNKSZ)                  // 8
#define MROWS (BATCH*LSEQ)                     // 4096
#define EPSF 1e-5f

typedef __attribute__((ext_vector_type(8))) short shortx8;
typedef __attribute__((ext_vector_type(4))) short shortx4;
typedef __attribute__((ext_vector_type(4))) float floatx4;

__device__ __forceinline__ ushort f2bf(float f) {
  unsigned u = __float_as_uint(f);
  unsigned r = (u + 0x7fffu + ((u >> 16) & 1u)) >> 16;
  return (ushort)r;
}

__device__ __forceinline__ shortx8 pack8(float4 a, float4 b) {
  shortx8 r;
  r[0] = (short)f2bf(a.x); r[1] = (short)f2bf(a.y);
  r[2] = (short)f2bf(a.z); r[3] = (short)f2bf(a.w);
  r[4] = (short)f2bf(b.x); r[5] = (short)f2bf(b.y);
  r[6] = (short)f2bf(b.z); r[7] = (short)f2bf(b.w);
  return r;
}

__device__ __forceinline__ void async_load16(const void* g, void* l) {
  __builtin_amdgcn_global_load_lds(
      (const __attribute__((address_space(1))) void*)g,
      (__attribute__((address_space(3))) void*)l, 16, 0, 0);
}

// ---------------- reductions ----------------
__device__ __forceinline__ float block_reduce_sum_256(float v, float* sb) {
  for (int off = 32; off > 0; off >>= 1) v += __shfl_down(v, off, 64);
  int lane = threadIdx.x & 63, wid = threadIdx.x >> 6;
  if (lane == 0) sb[wid] = v;
  __syncthreads();
  return sb[0] + sb[1] + sb[2] + sb[3];
}

// ---------------- fp32 -> bf16 (with zero tail padding) ----------------
__global__ __launch_bounds__(256) void cvt_bf16_k(const float* __restrict__ src,
                                                  ushort* __restrict__ dst,
                                                  size_t n_src, size_t n_dst) {
  size_t i = (size_t)blockIdx.x * 256 + threadIdx.x;
  if (i >= n_dst) return;
  float v = (i < n_src) ? src[i] : 0.f;
  dst[i] = f2bf(v);
}

// ---------------- rmsnorm (width 1024) -> bf16 out ----------------
__global__ __launch_bounds__(256) void rmsnorm_k(const float* __restrict__ x,
                                                 const float* __restrict__ w,
                                                 ushort* __restrict__ out) {
  __shared__ float sb[4];
  int r = blockIdx.x;
  const float* xr = x + (size_t)r * DMODEL;
  ushort* orow = out + (size_t)r * DMODEL;
  float v[4]; float ssq = 0.f;
  for (int i = 0; i < 4; i++) {
    v[i] = xr[threadIdx.x + i * 256];
    ssq += v[i] * v[i];
  }
  float s = block_reduce_sum_256(ssq, sb);
  float sc = rsqrtf(s / (float)DMODEL + EPSF);
  for (int i = 0; i < 4; i++) {
    int c = threadIdx.x + i * 256;
    orow[c] = f2bf(v[i] * sc * w[c]);
  }
}

// ---------------- MFMA bf16 NT GEMM (128x128 tile, BK=64) ----------------
__global__ __launch_bounds__(256) void gemm_nt_mfma(const ushort* __restrict__ A,
                                                    const ushort* __restrict__ B,
                                                    float* __restrict__ C,
                                                    const float* __restrict__ resid,
                                                    int M, int N, int K) {
  __shared__ ushort Asm[128 * 64];
  __shared__ ushort Bsm[128 * 64];
  int tid = threadIdx.x;
  int wid = tid >> 6, lane = tid & 63;
  int quad = lane >> 4, lrow = lane & 15;
  int m0 = blockIdx.y * 128, n0 = blockIdx.x * 128;
  int wm = (wid >> 1) * 64, wn = (wid & 1) * 64;
  floatx4 acc[4][4];
  for (int i = 0; i < 4; i++)
    for (int j = 0; j < 4; j++) acc[i][j] = (floatx4){0.f, 0.f, 0.f, 0.f};

  for (int k0 = 0; k0 < K; k0 += 64) {
    __syncthreads();
    for (int is = 0; is < 4; is++) {
      int boff = is * 4096 + wid * 1024;
      int bb = boff + lane * 16;
      int row = bb >> 7;
      int col = (bb & 127) >> 1;
      async_load16(A + (size_t)(m0 + row) * K + k0 + col, (char*)Asm + boff);
      async_load16(B + (size_t)(n0 + row) * K + k0 + col, (char*)Bsm + boff);
    }
    __syncthreads();
    for (int kk = 0; kk < 64; kk += 32) {
      shortx8 af[4], bf[4];
      for (int i = 0; i < 4; i++)
        af[i] = *(const shortx8*)&Asm[(wm + i * 16 + lrow) * 64 + kk + quad * 8];
      for (int j = 0; j < 4; j++)
        bf[j] = *(const shortx8*)&Bsm[(wn + j * 16 + lrow) * 64 + kk + quad * 8];
      for (int i = 0; i < 4; i++)
        for (int j = 0; j < 4; j++)
          acc[i][j] = __builtin_amdgcn_mfma_f32_16x16x32_bf16(af[i], bf[j], acc[i][j], 0, 0, 0);
    }
  }
  bool hasR = (resid != nullptr);
  for (int i = 0; i < 4; i++) {
    int r0 = m0 + wm + i * 16 + quad * 4;
    for (int j = 0; j < 4; j++) {
      int n = n0 + wn + j * 16 + lrow;
      if (n < N) {
        for (int r = 0; r < 4; r++) {
          size_t idx = (size_t)(r0 + r) * N + n;
          float v = acc[i][j][r];
          if (hasR) v += resid[idx];
          C[idx] = v;
        }
      }
    }
  }
}

// ---------------- depthwise conv + silu ----------------
__global__ __launch_bounds__(256) void conv_silu_k(const float* __restrict__ zx,
                                                   const float* __restrict__ cw,
                                                   const float* __restrict__ cb,
                                                   float* __restrict__ xBC) {
  int ch = blockIdx.x * 256 + threadIdx.x;
  if (ch >= CONVDIM) return;
  int r = blockIdx.y;
  int b = r >> 11, l = r & (LSEQ - 1);
  float acc = cb[ch];
  for (int k = 0; k < DCONV; k++) {
    int ls = l - (DCONV - 1) + k;
    if (ls >= 0)
      acc += zx[(size_t)(b * LSEQ + ls) * DINPROJ + DINNER + ch] * cw[ch * DCONV + k];
  }
  float s = acc / (1.f + expf(-acc));
  xBC[(size_t)r * CONVDIM + ch] = s;
}

// ---------------- dt softplus ----------------
__global__ __launch_bounds__(256) void dt_k(const float* __restrict__ zx,
                                            const float* __restrict__ dt_bias,
                                            float* __restrict__ dt_sp) {
  int g = blockIdx.x * 256 + threadIdx.x;
  int r = g >> 5, h = g & 31;
  float v = zx[(size_t)r * DINPROJ + DINNER + CONVDIM + h] + dt_bias[h];
  dt_sp[g] = (v > 20.f) ? v : log1pf(expf(v));
}

// ---------------- per-chunk inclusive cumsum of dt*A ----------------
__global__ __launch_bounds__(256) void cumsum_k(const float* __restrict__ dt_sp,
                                                const float* __restrict__ A_log,
                                                float* __restrict__ dtA_cs) {
  __shared__ float buf[256];
  int bid = blockIdx.x;
  int h = bid & 31, c = (bid >> 5) & 7, b = bid >> 8;
  int l = threadIdx.x;
  float Aneg = -expf(A_log[h]);
  int row = b * LSEQ + c * CHUNKSZ + l;
  buf[l] = dt_sp[row * 32 + h] * Aneg;
  __syncthreads();
  for (int off = 1; off < 256; off <<= 1) {
    float add = (l >= off) ? buf[l - off] : 0.f;
    __syncthreads();
    buf[l] += add;
    __syncthreads();
  }
  dtA_cs[(size_t)bid * CHUNKSZ + l] = buf[l];
}

// ---------------- per-chunk end states ----------------
__global__ __launch_bounds__(256) void states_k(const float* __restrict__ xBC,
                                                const float* __restrict__ dt_sp,
                                                const float* __restrict__ dtA_cs,
                                                float* __restrict__ st_raw) {
  __shared__ __align__(16) float Bs[64][68];
  __shared__ __align__(16) float Xs[64][68];
  __shared__ float wrow[64];
  int bid = blockIdx.x;
  int h = bid & 31, c = (bid >> 5) & 7, b = bid >> 8;
  int tid = threadIdx.x;
  int cbase = bid * CHUNKSZ;
  int rowbase = b * LSEQ + c * CHUNKSZ;
  float T = dtA_cs[cbase + CHUNKSZ - 1];
  float acc[16] = {};
  int n = tid & 63, pb = (tid >> 6) * 16;
  for (int lt = 0; lt < 4; lt++) {
    if (tid < 64) {
      int row = rowbase + lt * 64 + tid;
      wrow[tid] = dt_sp[row * 32 + h] * expf(T - dtA_cs[cbase + lt * 64 + tid]);
    }
    __syncthreads();
    for (int i = 0; i < 16; i++) {
      int idx = tid + i * 256;
      int l = idx >> 6, col = idx & 63;
      int row = rowbase + lt * 64 + l;
      Bs[l][col] = xBC[(size_t)row * CONVDIM + DINNER + col];
      Xs[l][col] = xBC[(size_t)row * CONVDIM + h * DHEAD + col] * wrow[l];
    }
    __syncthreads();
    for (int l = 0; l < 64; l++) {
      float bv = Bs[l][n];
      const float4* xp = reinterpret_cast<const float4*>(&Xs[l][0]);
      float4 x0 = xp[pb / 4 + 0], x1 = xp[pb / 4 + 1], x2 = xp[pb / 4 + 2], x3 = xp[pb / 4 + 3];
      acc[0] += x0.x * bv; acc[1] += x0.y * bv; acc[2] += x0.z * bv; acc[3] += x0.w * bv;
      acc[4] += x1.x * bv; acc[5] += x1.y * bv; acc[6] += x1.z * bv; acc[7] += x1.w * bv;
      acc[8] += x2.x * bv; acc[9] += x2.y * bv; acc[10] += x2.z * bv; acc[11] += x2.w * bv;
      acc[12] += x3.x * bv; acc[13] += x3.y * bv; acc[14] += x3.z * bv; acc[15] += x3.w * bv;
    }
    __syncthreads();
  }
  size_t base = (size_t)bid * (DHEAD * DSTATE);
  for (int j = 0; j < 16; j++) st_raw[base + (size_t)(pb + j) * 64 + n] = acc[j];
}

// ---------------- inter-chunk scan (in-place) ----------------
__global__ __launch_bounds__(256) void scan_k(float* __restrict__ st,
                                              const float* __restrict__ dtA_cs) {
  int bid = blockIdx.x;
  int h = bid & 31, b = bid >> 5;
  int tid = threadIdx.x;
  float s[16];
  for (int i = 0; i < 16; i++) s[i] = 0.f;
  for (int c = 0; c < NCHUNK; c++) {
    int g = (b * NCHUNK + c) * 32 + h;
    float dec = expf(dtA_cs[(size_t)g * CHUNKSZ + CHUNKSZ - 1]);
    size_t base = (size_t)g * (DHEAD * DSTATE);
    for (int i = 0; i < 16; i++) {
      int idx = tid + i * 256;
      float raw = st[base + idx];
      st[base + idx] = s[i];
      s[i] = s[i] * dec + raw;
    }
  }
}

// ---------------- MFMA ydiag: Y = (mask.decay.(C Bt)) @ Xdt + e^cs (C st^T) ----------------
#define BS_STRIDE 72
#define XT_STRIDE 68
#define PW_STRIDE 72
__global__ __launch_bounds__(256) void ydiag_mfma(const float* __restrict__ xBC,
                                                  const float* __restrict__ dt_sp,
                                                  const float* __restrict__ dtA_cs,
                                                  const float* __restrict__ st_in,
                                                  float* __restrict__ Y) {
  __shared__ ushort Bs[64 * BS_STRIDE];       // 9216 B
  __shared__ ushort XsT[64 * XT_STRIDE];      // 8704 B
  __shared__ ushort Pw[4 * 16 * PW_STRIDE];   // 9216 B
  __shared__ float cs[256];
  int tid = threadIdx.x;
  int w = tid >> 6, lane = tid & 63;
  int quad = lane >> 4, lrow = lane & 15;
  int bid = blockIdx.x;
  int lt = bid & 3, h = (bid >> 2) & 31, c = (bid >> 7) & 7, b = bid >> 10;
  int g = (b * NCHUNK + c) * 32 + h;
  int cbase = g * CHUNKSZ;
  int rowbase = b * LSEQ + c * CHUNKSZ;

  cs[tid] = dtA_cs[cbase + tid];
  __syncthreads();

  int mrow = lt * 64 + w * 16;  // chunk-local base row of this wave's m-tile
  float csl[4];
  for (int r = 0; r < 4; r++) csl[r] = cs[mrow + quad * 4 + r];

  // C A-frags (m = l rows, k = n_state)
  shortx8 Cf[2];
  {
    const float* cp = xBC + (size_t)(rowbase + mrow + lrow) * CONVDIM + DINNER + DSTATE;
    for (int q = 0; q < 2; q++) {
      float4 f0 = *(const float4*)(cp + q * 32 + quad * 8);
      float4 f1 = *(const float4*)(cp + q * 32 + quad * 8 + 4);
      Cf[q] = pack8(f0, f1);
    }
  }

  // Y_off first: acc = C @ st_in^T, then scale row l by exp(cs_l)
  floatx4 acc[4];
  for (int jt = 0; jt < 4; jt++) acc[jt] = (floatx4){0.f, 0.f, 0.f, 0.f};
  const float* stp = st_in + (size_t)g * (DHEAD * DSTATE);
  for (int q = 0; q < 2; q++) {
    for (int jt = 0; jt < 4; jt++) {
      const float* sp = stp + (size_t)(jt * 16 + lrow) * 64 + q * 32 + quad * 8;
      shortx8 sf = pack8(*(const float4*)sp, *(const float4*)(sp + 4));
      acc[jt] = __builtin_amdgcn_mfma_f32_16x16x32_bf16(Cf[q], sf, acc[jt], 0, 0, 0);
    }
  }
  for (int jt = 0; jt < 4; jt++)
    for (int r = 0; r < 4; r++) acc[jt][r] *= __expf(csl[r]);

  ushort* myP = Pw + w * 16 * PW_STRIDE;
  for (int st = 0; st <= lt; st++) {
    __syncthreads();
    {
      int nn = tid & 63, s4 = tid >> 6;
      for (int pass = 0; pass < 16; pass++) {
        int sr = s4 + pass * 4;
        int row = rowbase + st * 64 + sr;
        Bs[sr * BS_STRIDE + nn] = f2bf(xBC[(size_t)row * CONVDIM + DINNER + nn]);
        float dtv = dt_sp[row * 32 + h];
        XsT[nn * XT_STRIDE + sr] = f2bf(xBC[(size_t)row * CONVDIM + h * DHEAD + nn] * dtv);
      }
    }
    __syncthreads();
    // scores S[l][s] for this s-tile, masked+decayed -> Pw (bf16)
    for (int jt = 0; jt < 4; jt++) {
      floatx4 s = (floatx4){0.f, 0.f, 0.f, 0.f};
      for (int q = 0; q < 2; q++) {
        shortx8 bfr = *(const shortx8*)&Bs[(jt * 16 + lrow) * BS_STRIDE + q * 32 + quad * 8];
        s = __builtin_amdgcn_mfma_f32_16x16x32_bf16(Cf[q], bfr, s, 0, 0, 0);
      }
      int scol = st * 64 + jt * 16 + lrow;
      float css = cs[scol];
      for (int r = 0; r < 4; r++) {
        int l = mrow + quad * 4 + r;
        float v = (scol <= l) ? s[r] * __expf(csl[r] - css) : 0.f;
        myP[(quad * 4 + r) * PW_STRIDE + jt * 16 + lrow] = f2bf(v);
      }
    }
    // P @ Xdt  (wave-local LDS round-trip; lgkmcnt handled by compiler)
    shortx8 pf[2];
    for (int q = 0; q < 2; q++)
      pf[q] = *(const shortx8*)&myP[lrow * PW_STRIDE + q * 32 + quad * 8];
    for (int jt = 0; jt < 4; jt++) {
      for (int q = 0; q < 2; q++) {
        const ushort* xp = &XsT[(jt * 16 + lrow) * XT_STRIDE + q * 32 + quad * 8];
        shortx4 lo = *(const shortx4*)xp;
        shortx4 hi = *(const shortx4*)(xp + 4);
        shortx8 xf = __builtin_shufflevector(lo, hi, 0, 1, 2, 3, 4, 5, 6, 7);
        acc[jt] = __builtin_amdgcn_mfma_f32_16x16x32_bf16(pf[q], xf, acc[jt], 0, 0, 0);
      }
    }
  }
  int growb = rowbase + mrow + quad * 4;
  for (int jt = 0; jt < 4; jt++)
    for (int r = 0; r < 4; r++)
      Y[(size_t)(growb + r) * DINNER + h * DHEAD + jt * 16 + lrow] = acc[jt][r];
}

// ---------------- gated rmsnorm (+ D*X skip) -> bf16 out ----------------
__global__ __launch_bounds__(256) void gatenorm_k(const float* __restrict__ Y,
                                                  const float* __restrict__ zx,
                                                  const float* __restrict__ xBC,
                                                  const float* __restrict__ Dvec,
                                                  const float* __restrict__ gw,
                                                  ushort* __restrict__ ybf) {
  __shared__ float sb[4];
  int r = blockIdx.x;
  const float* yr = Y + (size_t)r * DINNER;
  const float* zr = zx + (size_t)r * DINPROJ;
  const float* xr = xBC + (size_t)r * CONVDIM;
  ushort* orow = ybf + (size_t)r * DINNER;
  float t[8]; float ssq = 0.f;
  for (int i = 0; i < 8; i++) {
    int cc = threadIdx.x + i * 256;
    float z = zr[cc];
    float yv = yr[cc] + Dvec[cc >> 6] * xr[cc];
    float gv = yv * (z / (1.f + expf(-z)));
    t[i] = gv;
    ssq += gv * gv;
  }
  float s = block_reduce_sum_256(ssq, sb);
  float sc = rsqrtf(s / (float)DINNER + EPSF);
  for (int i = 0; i < 8; i++) {
    int cc = threadIdx.x + i * 256;
    orow[cc] = f2bf(t[i] * sc * gw[cc]);
  }
}

// ---------------- launch ----------------
extern "C" void kernel_launch(void* const* d_in, const int* in_sizes, int n_in,
                              void* d_out, int out_size, void* d_ws, size_t ws_size,
                              hipStream_t stream) {
  const float* x_in     = (const float*)d_in[0];
  const float* in_w     = (const float*)d_in[1];
  const float* conv_w   = (const float*)d_in[2];
  const float* conv_b   = (const float*)d_in[3];
  const float* dt_bias  = (const float*)d_in[4];
  const float* A_log    = (const float*)d_in[5];
  const float* Dvec     = (const float*)d_in[6];
  const float* gnorm_w  = (const float*)d_in[7];
  const float* out_w    = (const float*)d_in[8];
  const float* rms_w    = (const float*)d_in[9];
  float* out = (float*)d_out;

  float* ws = (float*)d_ws;
  size_t o = 0;
  float* x_cur  = ws + o; o += (size_t)MROWS * DMODEL;
  float* zx     = ws + o; o += (size_t)MROWS * DINPROJ;
  float* xBC    = ws + o; o += (size_t)MROWS * CONVDIM;
  float* dt_sp  = ws + o; o += (size_t)MROWS * NHEADS;
  float* dtA_cs = ws + o; o += (size_t)BATCH * NCHUNK * NHEADS * CHUNKSZ;
  float* st     = ws + o; o += (size_t)BATCH * NCHUNK * NHEADS * DHEAD * DSTATE;
  float* Ybuf   = ws + o; o += (size_t)MROWS * DINNER;
  ushort* act_bf = (ushort*)(ws + o); o += (size_t)MROWS * DINNER / 2;
  ushort* w_bf   = (ushort*)(ws + o); o += (size_t)DINPROJ_PAD * DMODEL / 2;

  hipMemcpyAsync(x_cur, x_in, (size_t)MROWS * DMODEL * sizeof(float),
                 hipMemcpyDeviceToDevice, stream);

  for (int i = 0; i < 4; i++) {
    const float* in_w_i   = in_w    + (size_t)i * DINPROJ * DMODEL;
    const float* conv_w_i = conv_w  + (size_t)i * CONVDIM * DCONV;
    const float* conv_b_i = conv_b  + (size_t)i * CONVDIM;
    const float* dtb_i    = dt_bias + (size_t)i * NHEADS;
    const float* Alog_i   = A_log   + (size_t)i * NHEADS;
    const float* D_i      = Dvec    + (size_t)i * NHEADS;
    const float* gw_i     = gnorm_w + (size_t)i * DINNER;
    const float* out_w_i  = out_w   + (size_t)i * DMODEL * DINNER;
    const float* rms_w_i  = rms_w   + (size_t)i * DMODEL;

    {
      size_t ns = (size_t)DINPROJ * DMODEL, nd = (size_t)DINPROJ_PAD * DMODEL;
      cvt_bf16_k<<<(nd + 255) / 256, 256, 0, stream>>>(in_w_i, w_bf, ns, nd);
    }
    rmsnorm_k<<<MROWS, 256, 0, stream>>>(x_cur, rms_w_i, act_bf);
    gemm_nt_mfma<<<dim3(DINPROJ_PAD / 128, MROWS / 128), 256, 0, stream>>>(
        act_bf, w_bf, zx, nullptr, MROWS, DINPROJ, DMODEL);
    conv_silu_k<<<dim3((CONVDIM + 255) / 256, MROWS), 256, 0, stream>>>(
        zx, conv_w_i, conv_b_i, xBC);
    dt_k<<<MROWS * NHEADS / 256, 256, 0, stream>>>(zx, dtb_i, dt_sp);
    cumsum_k<<<BATCH * NCHUNK * NHEADS, 256, 0, stream>>>(dt_sp, Alog_i, dtA_cs);
    states_k<<<BATCH * NCHUNK * NHEADS, 256, 0, stream>>>(xBC, dt_sp, dtA_cs, st);
    scan_k<<<BATCH * NHEADS, 256, 0, stream>>>(st, dtA_cs);
    ydiag_mfma<<<BATCH * NCHUNK * NHEADS * 4, 256, 0, stream>>>(
        xBC, dt_sp, dtA_cs, st, Ybuf);
    gatenorm_k<<<MROWS, 256, 0, stream>>>(Ybuf, zx, xBC, D_i, gw_i, act_bf);
    {
      size_t ns = (size_t)DMODEL * DINNER;
      cvt_bf16_k<<<(ns + 255) / 256, 256, 0, stream>>>(out_w_i, w_bf, ns, ns);
    }
    float* outC = (i == 3) ? out : x_cur;
    gemm_nt_mfma<<<dim3(DMODEL / 128, MROWS / 128), 256, 0, stream>>>(
        act_bf, w_bf, outC, x_cur, MROWS, DMODEL, DINNER);
  }
}

// Round 4
// 1232.400 us; speedup vs baseline: 4.3010x; 1.1136x over previous
//
#include <hip/hip_runtime.h>
#include <cmath>

#define BATCH 2
#define LSEQ 2048
#define DMODEL 1024
#define DINNER 2048
#define NHEADS 32
#define DHEAD 64
#define DSTATE 64
#define DCONV 4
#define CONVDIM (DINNER + 2*DSTATE)            // 2176
#define DINPROJ (2*DINNER + 2*DSTATE + NHEADS) // 4256
#define DINPROJ_PAD 4352                       // 34*128
#define CHUNKSZ 256
#define NCHUNK (LSEQ/CHUNKSZ)                  // 8
#define MROWS (BATCH*LSEQ)                     // 4096
#define EPSF 1e-5f

typedef __attribute__((ext_vector_type(8))) short shortx8;
typedef __attribute__((ext_vector_type(4))) short shortx4;
typedef __attribute__((ext_vector_type(4))) float floatx4;

__device__ __forceinline__ ushort f2bf(float f) {
  unsigned u = __float_as_uint(f);
  unsigned r = (u + 0x7fffu + ((u >> 16) & 1u)) >> 16;
  return (ushort)r;
}

__device__ __forceinline__ shortx8 pack8(float4 a, float4 b) {
  shortx8 r;
  r[0] = (short)f2bf(a.x); r[1] = (short)f2bf(a.y);
  r[2] = (short)f2bf(a.z); r[3] = (short)f2bf(a.w);
  r[4] = (short)f2bf(b.x); r[5] = (short)f2bf(b.y);
  r[6] = (short)f2bf(b.z); r[7] = (short)f2bf(b.w);
  return r;
}

__device__ __forceinline__ void async_load16(const void* g, void* l) {
  __builtin_amdgcn_global_load_lds(
      (const __attribute__((address_space(1))) void*)g,
      (__attribute__((address_space(3))) void*)l, 16, 0, 0);
}

// ---------------- reductions ----------------
__device__ __forceinline__ float block_reduce_sum_256(float v, float* sb) {
  for (int off = 32; off > 0; off >>= 1) v += __shfl_down(v, off, 64);
  int lane = threadIdx.x & 63, wid = threadIdx.x >> 6;
  if (lane == 0) sb[wid] = v;
  __syncthreads();
  return sb[0] + sb[1] + sb[2] + sb[3];
}

// ---------------- fp32 -> bf16 (with zero tail padding) ----------------
__global__ __launch_bounds__(256) void cvt_bf16_k(const float* __restrict__ src,
                                                  ushort* __restrict__ dst,
                                                  size_t n_src, size_t n_dst) {
  size_t i = (size_t)blockIdx.x * 256 + threadIdx.x;
  if (i >= n_dst) return;
  float v = (i < n_src) ? src[i] : 0.f;
  dst[i] = f2bf(v);
}

// ---------------- rmsnorm (width 1024) -> bf16 out ----------------
__global__ __launch_bounds__(256) void rmsnorm_k(const float* __restrict__ x,
                                                 const float* __restrict__ w,
                                                 ushort* __restrict__ out) {
  __shared__ float sb[4];
  int r = blockIdx.x;
  const float* xr = x + (size_t)r * DMODEL;
  ushort* orow = out + (size_t)r * DMODEL;
  float v[4]; float ssq = 0.f;
  for (int i = 0; i < 4; i++) {
    v[i] = xr[threadIdx.x + i * 256];
    ssq += v[i] * v[i];
  }
  float s = block_reduce_sum_256(ssq, sb);
  float sc = rsqrtf(s / (float)DMODEL + EPSF);
  for (int i = 0; i < 4; i++) {
    int c = threadIdx.x + i * 256;
    orow[c] = f2bf(v[i] * sc * w[c]);
  }
}

// ---------------- MFMA bf16 NT GEMM (128x128 tile, BK=64, XOR-swizzled LDS) ----------------
// LDS byte (row, cb) holds global column (cb ^ ((row&7)<<4)); un-applied at ds_read.
__global__ __launch_bounds__(256) void gemm_nt_mfma(const ushort* __restrict__ A,
                                                    const ushort* __restrict__ B,
                                                    float* __restrict__ C,
                                                    const float* __restrict__ resid,
                                                    int M, int N, int K) {
  __shared__ ushort Asm[128 * 64];
  __shared__ ushort Bsm[128 * 64];
  int tid = threadIdx.x;
  int wid = tid >> 6, lane = tid & 63;
  int quad = lane >> 4, lrow = lane & 15;
  int m0 = blockIdx.y * 128, n0 = blockIdx.x * 128;
  int wm = (wid >> 1) * 64, wn = (wid & 1) * 64;
  floatx4 acc[4][4];
  for (int i = 0; i < 4; i++)
    for (int j = 0; j < 4; j++) acc[i][j] = (floatx4){0.f, 0.f, 0.f, 0.f};

  for (int k0 = 0; k0 < K; k0 += 64) {
    __syncthreads();
    for (int is = 0; is < 4; is++) {
      int boff = is * 4096 + wid * 1024;        // wave-uniform LDS base
      int bb = boff + lane * 16;                // this lane's LDS byte
      int row = bb >> 7;                        // tile row (128B per row)
      int cb = bb & 127;
      int col = (cb ^ ((row & 7) << 4)) >> 1;   // swizzled source column
      async_load16(A + (size_t)(m0 + row) * K + k0 + col, (char*)Asm + boff);
      async_load16(B + (size_t)(n0 + row) * K + k0 + col, (char*)Bsm + boff);
    }
    __syncthreads();
    for (int kk = 0; kk < 64; kk += 32) {
      shortx8 af[4], bf[4];
      for (int i = 0; i < 4; i++) {
        int r = wm + i * 16 + lrow;
        int cbyte = ((kk + quad * 8) * 2) ^ ((r & 7) << 4);
        af[i] = *(const shortx8*)((const char*)Asm + r * 128 + cbyte);
      }
      for (int j = 0; j < 4; j++) {
        int r = wn + j * 16 + lrow;
        int cbyte = ((kk + quad * 8) * 2) ^ ((r & 7) << 4);
        bf[j] = *(const shortx8*)((const char*)Bsm + r * 128 + cbyte);
      }
      for (int i = 0; i < 4; i++)
        for (int j = 0; j < 4; j++)
          acc[i][j] = __builtin_amdgcn_mfma_f32_16x16x32_bf16(af[i], bf[j], acc[i][j], 0, 0, 0);
    }
  }
  bool hasR = (resid != nullptr);
  for (int i = 0; i < 4; i++) {
    int r0 = m0 + wm + i * 16 + quad * 4;
    for (int j = 0; j < 4; j++) {
      int n = n0 + wn + j * 16 + lrow;
      if (n < N) {
        for (int r = 0; r < 4; r++) {
          size_t idx = (size_t)(r0 + r) * N + n;
          float v = acc[i][j][r];
          if (hasR) v += resid[idx];
          C[idx] = v;
        }
      }
    }
  }
}

// ---------------- depthwise conv + silu ----------------
__global__ __launch_bounds__(256) void conv_silu_k(const float* __restrict__ zx,
                                                   const float* __restrict__ cw,
                                                   const float* __restrict__ cb,
                                                   float* __restrict__ xBC) {
  int ch = blockIdx.x * 256 + threadIdx.x;
  if (ch >= CONVDIM) return;
  int r = blockIdx.y;
  int b = r >> 11, l = r & (LSEQ - 1);
  float acc = cb[ch];
  for (int k = 0; k < DCONV; k++) {
    int ls = l - (DCONV - 1) + k;
    if (ls >= 0)
      acc += zx[(size_t)(b * LSEQ + ls) * DINPROJ + DINNER + ch] * cw[ch * DCONV + k];
  }
  float s = acc / (1.f + expf(-acc));
  xBC[(size_t)r * CONVDIM + ch] = s;
}

// ---------------- dt softplus ----------------
__global__ __launch_bounds__(256) void dt_k(const float* __restrict__ zx,
                                            const float* __restrict__ dt_bias,
                                            float* __restrict__ dt_sp) {
  int g = blockIdx.x * 256 + threadIdx.x;
  int r = g >> 5, h = g & 31;
  float v = zx[(size_t)r * DINPROJ + DINNER + CONVDIM + h] + dt_bias[h];
  dt_sp[g] = (v > 20.f) ? v : log1pf(expf(v));
}

// ---------------- per-chunk inclusive cumsum of dt*A ----------------
__global__ __launch_bounds__(256) void cumsum_k(const float* __restrict__ dt_sp,
                                                const float* __restrict__ A_log,
                                                float* __restrict__ dtA_cs) {
  __shared__ float buf[256];
  int bid = blockIdx.x;
  int h = bid & 31, c = (bid >> 5) & 7, b = bid >> 8;
  int l = threadIdx.x;
  float Aneg = -expf(A_log[h]);
  int row = b * LSEQ + c * CHUNKSZ + l;
  buf[l] = dt_sp[row * 32 + h] * Aneg;
  __syncthreads();
  for (int off = 1; off < 256; off <<= 1) {
    float add = (l >= off) ? buf[l - off] : 0.f;
    __syncthreads();
    buf[l] += add;
    __syncthreads();
  }
  dtA_cs[(size_t)bid * CHUNKSZ + l] = buf[l];
}

// ---------------- MFMA per-chunk end states: st[p][n] = sum_l (Xdt*decay)[l,p] B[l,n] ----------------
#define ST_STRIDE 72
__global__ __launch_bounds__(256) void states_mfma(const float* __restrict__ xBC,
                                                   const float* __restrict__ dt_sp,
                                                   const float* __restrict__ dtA_cs,
                                                   float* __restrict__ st_raw) {
  __shared__ ushort XT[64 * ST_STRIDE];  // [p][l] bf16
  __shared__ ushort BT[64 * ST_STRIDE];  // [n][l] bf16
  __shared__ float wrow[64];
  int bid = blockIdx.x;  // ((b*8+c)*32+h)
  int h = bid & 31, c = (bid >> 5) & 7, b = bid >> 8;
  int tid = threadIdx.x;
  int w = tid >> 6, lane = tid & 63;
  int quad = lane >> 4, lrow = lane & 15;
  int cbase = bid * CHUNKSZ;
  int rowbase = b * LSEQ + c * CHUNKSZ;
  float T = dtA_cs[cbase + CHUNKSZ - 1];
  floatx4 acc[4];
  for (int jt = 0; jt < 4; jt++) acc[jt] = (floatx4){0.f, 0.f, 0.f, 0.f};
  for (int lt = 0; lt < 4; lt++) {
    __syncthreads();
    if (tid < 64) {
      int row = rowbase + lt * 64 + tid;
      wrow[tid] = dt_sp[row * 32 + h] * __expf(T - dtA_cs[cbase + lt * 64 + tid]);
    }
    __syncthreads();
    {
      int nn = tid & 63, s4 = tid >> 6;
      for (int pass = 0; pass < 16; pass++) {
        int sr = s4 + pass * 4;  // chunk-local l within this 64-tile
        int row = rowbase + lt * 64 + sr;
        BT[nn * ST_STRIDE + sr] = f2bf(xBC[(size_t)row * CONVDIM + DINNER + nn]);
        XT[nn * ST_STRIDE + sr] = f2bf(xBC[(size_t)row * CONVDIM + h * DHEAD + nn] * wrow[sr]);
      }
    }
    __syncthreads();
    for (int kk = 0; kk < 64; kk += 32) {
      shortx8 af = *(const shortx8*)&XT[(w * 16 + lrow) * ST_STRIDE + kk + quad * 8];
      for (int jt = 0; jt < 4; jt++) {
        shortx8 bf = *(const shortx8*)&BT[(jt * 16 + lrow) * ST_STRIDE + kk + quad * 8];
        acc[jt] = __builtin_amdgcn_mfma_f32_16x16x32_bf16(af, bf, acc[jt], 0, 0, 0);
      }
    }
  }
  size_t base = (size_t)bid * (DHEAD * DSTATE);
  for (int jt = 0; jt < 4; jt++) {
    int n = jt * 16 + lrow;
    for (int r = 0; r < 4; r++) {
      int p = w * 16 + quad * 4 + r;
      st_raw[base + (size_t)p * 64 + n] = acc[jt][r];
    }
  }
}

// ---------------- inter-chunk scan (in-place) ----------------
__global__ __launch_bounds__(256) void scan_k(float* __restrict__ st,
                                              const float* __restrict__ dtA_cs) {
  int bid = blockIdx.x;
  int h = bid & 31, b = bid >> 5;
  int tid = threadIdx.x;
  float s[16];
  for (int i = 0; i < 16; i++) s[i] = 0.f;
  for (int c = 0; c < NCHUNK; c++) {
    int g = (b * NCHUNK + c) * 32 + h;
    float dec = expf(dtA_cs[(size_t)g * CHUNKSZ + CHUNKSZ - 1]);
    size_t base = (size_t)g * (DHEAD * DSTATE);
    for (int i = 0; i < 16; i++) {
      int idx = tid + i * 256;
      float raw = st[base + idx];
      st[base + idx] = s[i];
      s[i] = s[i] * dec + raw;
    }
  }
}

// ---------------- MFMA ydiag: Y = (mask.decay.(C Bt)) @ Xdt + e^cs (C st^T) ----------------
#define BS_STRIDE 72
#define XT_STRIDE 68
#define PW_STRIDE 72
__global__ __launch_bounds__(256) void ydiag_mfma(const float* __restrict__ xBC,
                                                  const float* __restrict__ dt_sp,
                                                  const float* __restrict__ dtA_cs,
                                                  const float* __restrict__ st_in,
                                                  float* __restrict__ Y) {
  __shared__ ushort Bs[64 * BS_STRIDE];
  __shared__ ushort XsT[64 * XT_STRIDE];
  __shared__ ushort Pw[4 * 16 * PW_STRIDE];
  __shared__ float cs[256];
  int tid = threadIdx.x;
  int w = tid >> 6, lane = tid & 63;
  int quad = lane >> 4, lrow = lane & 15;
  int bid = blockIdx.x;
  int lt = bid & 3, h = (bid >> 2) & 31, c = (bid >> 7) & 7, b = bid >> 10;
  int g = (b * NCHUNK + c) * 32 + h;
  int cbase = g * CHUNKSZ;
  int rowbase = b * LSEQ + c * CHUNKSZ;

  cs[tid] = dtA_cs[cbase + tid];
  __syncthreads();

  int mrow = lt * 64 + w * 16;
  float csl[4];
  for (int r = 0; r < 4; r++) csl[r] = cs[mrow + quad * 4 + r];

  shortx8 Cf[2];
  {
    const float* cp = xBC + (size_t)(rowbase + mrow + lrow) * CONVDIM + DINNER + DSTATE;
    for (int q = 0; q < 2; q++) {
      float4 f0 = *(const float4*)(cp + q * 32 + quad * 8);
      float4 f1 = *(const float4*)(cp + q * 32 + quad * 8 + 4);
      Cf[q] = pack8(f0, f1);
    }
  }

  floatx4 acc[4];
  for (int jt = 0; jt < 4; jt++) acc[jt] = (floatx4){0.f, 0.f, 0.f, 0.f};
  const float* stp = st_in + (size_t)g * (DHEAD * DSTATE);
  for (int q = 0; q < 2; q++) {
    for (int jt = 0; jt < 4; jt++) {
      const float* sp = stp + (size_t)(jt * 16 + lrow) * 64 + q * 32 + quad * 8;
      shortx8 sf = pack8(*(const float4*)sp, *(const float4*)(sp + 4));
      acc[jt] = __builtin_amdgcn_mfma_f32_16x16x32_bf16(Cf[q], sf, acc[jt], 0, 0, 0);
    }
  }
  for (int jt = 0; jt < 4; jt++)
    for (int r = 0; r < 4; r++) acc[jt][r] *= __expf(csl[r]);

  ushort* myP = Pw + w * 16 * PW_STRIDE;
  for (int st = 0; st <= lt; st++) {
    __syncthreads();
    {
      int nn = tid & 63, s4 = tid >> 6;
      for (int pass = 0; pass < 16; pass++) {
        int sr = s4 + pass * 4;
        int row = rowbase + st * 64 + sr;
        Bs[sr * BS_STRIDE + nn] = f2bf(xBC[(size_t)row * CONVDIM + DINNER + nn]);
        float dtv = dt_sp[row * 32 + h];
        XsT[nn * XT_STRIDE + sr] = f2bf(xBC[(size_t)row * CONVDIM + h * DHEAD + nn] * dtv);
      }
    }
    __syncthreads();
    for (int jt = 0; jt < 4; jt++) {
      floatx4 s = (floatx4){0.f, 0.f, 0.f, 0.f};
      for (int q = 0; q < 2; q++) {
        shortx8 bfr = *(const shortx8*)&Bs[(jt * 16 + lrow) * BS_STRIDE + q * 32 + quad * 8];
        s = __builtin_amdgcn_mfma_f32_16x16x32_bf16(Cf[q], bfr, s, 0, 0, 0);
      }
      int scol = st * 64 + jt * 16 + lrow;
      float css = cs[scol];
      for (int r = 0; r < 4; r++) {
        int l = mrow + quad * 4 + r;
        float v = (scol <= l) ? s[r] * __expf(csl[r] - css) : 0.f;
        myP[(quad * 4 + r) * PW_STRIDE + jt * 16 + lrow] = f2bf(v);
      }
    }
    shortx8 pf[2];
    for (int q = 0; q < 2; q++)
      pf[q] = *(const shortx8*)&myP[lrow * PW_STRIDE + q * 32 + quad * 8];
    for (int jt = 0; jt < 4; jt++) {
      for (int q = 0; q < 2; q++) {
        const ushort* xp = &XsT[(jt * 16 + lrow) * XT_STRIDE + q * 32 + quad * 8];
        shortx4 lo = *(const shortx4*)xp;
        shortx4 hi = *(const shortx4*)(xp + 4);
        shortx8 xf = __builtin_shufflevector(lo, hi, 0, 1, 2, 3, 4, 5, 6, 7);
        acc[jt] = __builtin_amdgcn_mfma_f32_16x16x32_bf16(pf[q], xf, acc[jt], 0, 0, 0);
      }
    }
  }
  int growb = rowbase + mrow + quad * 4;
  for (int jt = 0; jt < 4; jt++)
    for (int r = 0; r < 4; r++)
      Y[(size_t)(growb + r) * DINNER + h * DHEAD + jt * 16 + lrow] = acc[jt][r];
}

// ---------------- gated rmsnorm (+ D*X skip) -> bf16 out ----------------
__global__ __launch_bounds__(256) void gatenorm_k(const float* __restrict__ Y,
                                                  const float* __restrict__ zx,
                                                  const float* __restrict__ xBC,
                                                  const float* __restrict__ Dvec,
                                                  const float* __restrict__ gw,
                                                  ushort* __restrict__ ybf) {
  __shared__ float sb[4];
  int r = blockIdx.x;
  const float* yr = Y + (size_t)r * DINNER;
  const float* zr = zx + (size_t)r * DINPROJ;
  const float* xr = xBC + (size_t)r * CONVDIM;
  ushort* orow = ybf + (size_t)r * DINNER;
  float t[8]; float ssq = 0.f;
  for (int i = 0; i < 8; i++) {
    int cc = threadIdx.x + i * 256;
    float z = zr[cc];
    float yv = yr[cc] + Dvec[cc >> 6] * xr[cc];
    float gv = yv * (z / (1.f + expf(-z)));
    t[i] = gv;
    ssq += gv * gv;
  }
  float s = block_reduce_sum_256(ssq, sb);
  float sc = rsqrtf(s / (float)DINNER + EPSF);
  for (int i = 0; i < 8; i++) {
    int cc = threadIdx.x + i * 256;
    orow[cc] = f2bf(t[i] * sc * gw[cc]);
  }
}

// ---------------- launch ----------------
extern "C" void kernel_launch(void* const* d_in, const int* in_sizes, int n_in,
                              void* d_out, int out_size, void* d_ws, size_t ws_size,
                              hipStream_t stream) {
  const float* x_in     = (const float*)d_in[0];
  const float* in_w     = (const float*)d_in[1];
  const float* conv_w   = (const float*)d_in[2];
  const float* conv_b   = (const float*)d_in[3];
  const float* dt_bias  = (const float*)d_in[4];
  const float* A_log    = (const float*)d_in[5];
  const float* Dvec     = (const float*)d_in[6];
  const float* gnorm_w  = (const float*)d_in[7];
  const float* out_w    = (const float*)d_in[8];
  const float* rms_w    = (const float*)d_in[9];
  float* out = (float*)d_out;

  float* ws = (float*)d_ws;
  size_t o = 0;
  float* x_cur  = ws + o; o += (size_t)MROWS * DMODEL;
  float* zx     = ws + o; o += (size_t)MROWS * DINPROJ;
  float* xBC    = ws + o; o += (size_t)MROWS * CONVDIM;
  float* dt_sp  = ws + o; o += (size_t)MROWS * NHEADS;
  float* dtA_cs = ws + o; o += (size_t)BATCH * NCHUNK * NHEADS * CHUNKSZ;
  float* st     = ws + o; o += (size_t)BATCH * NCHUNK * NHEADS * DHEAD * DSTATE;
  float* Ybuf   = ws + o; o += (size_t)MROWS * DINNER;
  ushort* act_bf = (ushort*)(ws + o); o += (size_t)MROWS * DINNER / 2;
  ushort* w_bf   = (ushort*)(ws + o); o += (size_t)DINPROJ_PAD * DMODEL / 2;

  hipMemcpyAsync(x_cur, x_in, (size_t)MROWS * DMODEL * sizeof(float),
                 hipMemcpyDeviceToDevice, stream);

  for (int i = 0; i < 4; i++) {
    const float* in_w_i   = in_w    + (size_t)i * DINPROJ * DMODEL;
    const float* conv_w_i = conv_w  + (size_t)i * CONVDIM * DCONV;
    const float* conv_b_i = conv_b  + (size_t)i * CONVDIM;
    const float* dtb_i    = dt_bias + (size_t)i * NHEADS;
    const float* Alog_i   = A_log   + (size_t)i * NHEADS;
    const float* D_i      = Dvec    + (size_t)i * NHEADS;
    const float* gw_i     = gnorm_w + (size_t)i * DINNER;
    const float* out_w_i  = out_w   + (size_t)i * DMODEL * DINNER;
    const float* rms_w_i  = rms_w   + (size_t)i * DMODEL;

    {
      size_t ns = (size_t)DINPROJ * DMODEL, nd = (size_t)DINPROJ_PAD * DMODEL;
      cvt_bf16_k<<<(nd + 255) / 256, 256, 0, stream>>>(in_w_i, w_bf, ns, nd);
    }
    rmsnorm_k<<<MROWS, 256, 0, stream>>>(x_cur, rms_w_i, act_bf);
    gemm_nt_mfma<<<dim3(DINPROJ_PAD / 128, MROWS / 128), 256, 0, stream>>>(
        act_bf, w_bf, zx, nullptr, MROWS, DINPROJ, DMODEL);
    conv_silu_k<<<dim3((CONVDIM + 255) / 256, MROWS), 256, 0, stream>>>(
        zx, conv_w_i, conv_b_i, xBC);
    dt_k<<<MROWS * NHEADS / 256, 256, 0, stream>>>(zx, dtb_i, dt_sp);
    cumsum_k<<<BATCH * NCHUNK * NHEADS, 256, 0, stream>>>(dt_sp, Alog_i, dtA_cs);
    states_mfma<<<BATCH * NCHUNK * NHEADS, 256, 0, stream>>>(xBC, dt_sp, dtA_cs, st);
    scan_k<<<BATCH * NHEADS, 256, 0, stream>>>(st, dtA_cs);
    ydiag_mfma<<<BATCH * NCHUNK * NHEADS * 4, 256, 0, stream>>>(
        xBC, dt_sp, dtA_cs, st, Ybuf);
    gatenorm_k<<<MROWS, 256, 0, stream>>>(Ybuf, zx, xBC, D_i, gw_i, act_bf);
    {
      size_t ns = (size_t)DMODEL * DINNER;
      cvt_bf16_k<<<(ns + 255) / 256, 256, 0, stream>>>(out_w_i, w_bf, ns, ns);
    }
    float* outC = (i == 3) ? out : x_cur;
    gemm_nt_mfma<<<dim3(DMODEL / 128, MROWS / 128), 256, 0, stream>>>(
        act_bf, w_bf, outC, x_cur, MROWS, DMODEL, DINNER);
  }
}

// Round 5
// 1202.652 us; speedup vs baseline: 4.4074x; 1.0247x over previous
//
#include <hip/hip_runtime.h>
#include <cmath>

#define BATCH 2
#define LSEQ 2048
#define DMODEL 1024
#define DINNER 2048
#define NHEADS 32
#define DHEAD 64
#define DSTATE 64
#define DCONV 4
#define CONVDIM (DINNER + 2*DSTATE)            // 2176
#define DINPROJ (2*DINNER + 2*DSTATE + NHEADS) // 4256
#define DINPROJ_PAD 4352                       // 34*128
#define CHUNKSZ 256
#define NCHUNK (LSEQ/CHUNKSZ)                  // 8
#define MROWS (BATCH*LSEQ)                     // 4096
#define EPSF 1e-5f

typedef __attribute__((ext_vector_type(8))) short shortx8;
typedef __attribute__((ext_vector_type(4))) short shortx4;
typedef __attribute__((ext_vector_type(4))) float floatx4;

__device__ __forceinline__ ushort f2bf(float f) {
  unsigned u = __float_as_uint(f);
  unsigned r = (u + 0x7fffu + ((u >> 16) & 1u)) >> 16;
  return (ushort)r;
}
__device__ __forceinline__ float bf2f(ushort b) {
  return __uint_as_float(((unsigned)b) << 16);
}

__device__ __forceinline__ shortx8 pack8(float4 a, float4 b) {
  shortx8 r;
  r[0] = (short)f2bf(a.x); r[1] = (short)f2bf(a.y);
  r[2] = (short)f2bf(a.z); r[3] = (short)f2bf(a.w);
  r[4] = (short)f2bf(b.x); r[5] = (short)f2bf(b.y);
  r[6] = (short)f2bf(b.z); r[7] = (short)f2bf(b.w);
  return r;
}

__device__ __forceinline__ void async_load16(const void* g, void* l) {
  __builtin_amdgcn_global_load_lds(
      (const __attribute__((address_space(1))) void*)g,
      (__attribute__((address_space(3))) void*)l, 16, 0, 0);
}

// ---------------- reductions ----------------
__device__ __forceinline__ float block_reduce_sum_256(float v, float* sb) {
  for (int off = 32; off > 0; off >>= 1) v += __shfl_down(v, off, 64);
  int lane = threadIdx.x & 63, wid = threadIdx.x >> 6;
  if (lane == 0) sb[wid] = v;
  __syncthreads();
  return sb[0] + sb[1] + sb[2] + sb[3];
}

// ---------------- fp32 -> bf16 (with zero tail padding) ----------------
__global__ __launch_bounds__(256) void cvt_bf16_k(const float* __restrict__ src,
                                                  ushort* __restrict__ dst,
                                                  size_t n_src, size_t n_dst) {
  size_t i = (size_t)blockIdx.x * 256 + threadIdx.x;
  if (i >= n_dst) return;
  float v = (i < n_src) ? src[i] : 0.f;
  dst[i] = f2bf(v);
}

// ---------------- rmsnorm (width 1024) -> bf16 out ----------------
__global__ __launch_bounds__(256) void rmsnorm_k(const float* __restrict__ x,
                                                 const float* __restrict__ w,
                                                 ushort* __restrict__ out) {
  __shared__ float sb[4];
  int r = blockIdx.x;
  const float* xr = x + (size_t)r * DMODEL;
  ushort* orow = out + (size_t)r * DMODEL;
  float v[4]; float ssq = 0.f;
  for (int i = 0; i < 4; i++) {
    v[i] = xr[threadIdx.x + i * 256];
    ssq += v[i] * v[i];
  }
  float s = block_reduce_sum_256(ssq, sb);
  float sc = rsqrtf(s / (float)DMODEL + EPSF);
  for (int i = 0; i < 4; i++) {
    int c = threadIdx.x + i * 256;
    orow[c] = f2bf(v[i] * sc * w[c]);
  }
}

// ---------------- MFMA bf16 NT GEMM (128x128 tile, BK=64, XOR-swizzled LDS, supertiled) ----------------
__global__ __launch_bounds__(256) void gemm_nt_mfma(const ushort* __restrict__ A,
                                                    const ushort* __restrict__ B,
                                                    float* __restrict__ C,
                                                    const float* __restrict__ resid,
                                                    int M, int N, int K) {
  __shared__ ushort Asm[128 * 64];
  __shared__ ushort Bsm[128 * 64];
  int tid = threadIdx.x;
  int wid = tid >> 6, lane = tid & 63;
  int quad = lane >> 4, lrow = lane & 15;

  // supertile swizzle: groups of 8 m-blocks, n-major inside -> L2 reuse of B
  int nbx = gridDim.x;
  int lin = blockIdx.y * nbx + blockIdx.x;
  int span = 8 * nbx;
  int sup = lin / span, rem = lin - sup * span;
  int rowsS = gridDim.y - sup * 8; if (rowsS > 8) rowsS = 8;
  int mb = sup * 8 + rem % rowsS;
  int nb = rem / rowsS;

  int m0 = mb * 128, n0 = nb * 128;
  int wm = (wid >> 1) * 64, wn = (wid & 1) * 64;
  floatx4 acc[4][4];
  for (int i = 0; i < 4; i++)
    for (int j = 0; j < 4; j++) acc[i][j] = (floatx4){0.f, 0.f, 0.f, 0.f};

  for (int k0 = 0; k0 < K; k0 += 64) {
    __syncthreads();
    for (int is = 0; is < 4; is++) {
      int boff = is * 4096 + wid * 1024;        // wave-uniform LDS base
      int bb = boff + lane * 16;                // this lane's LDS byte
      int row = bb >> 7;                        // tile row (128B per row)
      int cb = bb & 127;
      int col = (cb ^ ((row & 7) << 4)) >> 1;   // swizzled source column
      async_load16(A + (size_t)(m0 + row) * K + k0 + col, (char*)Asm + boff);
      async_load16(B + (size_t)(n0 + row) * K + k0 + col, (char*)Bsm + boff);
    }
    __syncthreads();
    for (int kk = 0; kk < 64; kk += 32) {
      shortx8 af[4], bf[4];
      for (int i = 0; i < 4; i++) {
        int r = wm + i * 16 + lrow;
        int cbyte = ((kk + quad * 8) * 2) ^ ((r & 7) << 4);
        af[i] = *(const shortx8*)((const char*)Asm + r * 128 + cbyte);
      }
      for (int j = 0; j < 4; j++) {
        int r = wn + j * 16 + lrow;
        int cbyte = ((kk + quad * 8) * 2) ^ ((r & 7) << 4);
        bf[j] = *(const shortx8*)((const char*)Bsm + r * 128 + cbyte);
      }
      for (int i = 0; i < 4; i++)
        for (int j = 0; j < 4; j++)
          acc[i][j] = __builtin_amdgcn_mfma_f32_16x16x32_bf16(af[i], bf[j], acc[i][j], 0, 0, 0);
    }
  }
  bool hasR = (resid != nullptr);
  for (int i = 0; i < 4; i++) {
    int r0 = m0 + wm + i * 16 + quad * 4;
    for (int j = 0; j < 4; j++) {
      int n = n0 + wn + j * 16 + lrow;
      if (n < N) {
        for (int r = 0; r < 4; r++) {
          size_t idx = (size_t)(r0 + r) * N + n;
          float v = acc[i][j][r];
          if (hasR) v += resid[idx];
          C[idx] = v;
        }
      }
    }
  }
}

// ---------------- depthwise conv + silu -> bf16 xBC ----------------
__global__ __launch_bounds__(256) void conv_silu_k(const float* __restrict__ zx,
                                                   const float* __restrict__ cw,
                                                   const float* __restrict__ cb,
                                                   ushort* __restrict__ xbf) {
  int ch = blockIdx.x * 256 + threadIdx.x;
  if (ch >= CONVDIM) return;
  int r = blockIdx.y;
  int b = r >> 11, l = r & (LSEQ - 1);
  float acc = cb[ch];
  for (int k = 0; k < DCONV; k++) {
    int ls = l - (DCONV - 1) + k;
    if (ls >= 0)
      acc += zx[(size_t)(b * LSEQ + ls) * DINPROJ + DINNER + ch] * cw[ch * DCONV + k];
  }
  float s = acc / (1.f + expf(-acc));
  xbf[(size_t)r * CONVDIM + ch] = f2bf(s);
}

// ---------------- fused dt softplus + per-chunk inclusive cumsum of dt*A ----------------
__global__ __launch_bounds__(256) void cumsum_k(const float* __restrict__ zx,
                                                const float* __restrict__ dt_bias,
                                                const float* __restrict__ A_log,
                                                float* __restrict__ dt_sp,
                                                float* __restrict__ dtA_cs) {
  __shared__ float buf[256];
  int bid = blockIdx.x;  // ((b*8+c)*32+h)
  int h = bid & 31, c = (bid >> 5) & 7, b = bid >> 8;
  int l = threadIdx.x;
  float Aneg = -expf(A_log[h]);
  int row = b * LSEQ + c * CHUNKSZ + l;
  float v = zx[(size_t)row * DINPROJ + DINNER + CONVDIM + h] + dt_bias[h];
  float dtv = (v > 20.f) ? v : log1pf(expf(v));
  dt_sp[row * 32 + h] = dtv;
  buf[l] = dtv * Aneg;
  __syncthreads();
  for (int off = 1; off < 256; off <<= 1) {
    float add = (l >= off) ? buf[l - off] : 0.f;
    __syncthreads();
    buf[l] += add;
    __syncthreads();
  }
  dtA_cs[(size_t)bid * CHUNKSZ + l] = buf[l];
}

// ---------------- MFMA per-chunk end states: st[p][n] = sum_l (Xdt*decay)[l,p] B[l,n] ----------------
#define ST_STRIDE 72
__global__ __launch_bounds__(256) void states_mfma(const ushort* __restrict__ xbf,
                                                   const float* __restrict__ dt_sp,
                                                   const float* __restrict__ dtA_cs,
                                                   float* __restrict__ st_raw) {
  __shared__ ushort XT[64 * ST_STRIDE];  // [p][l] bf16
  __shared__ ushort BT[64 * ST_STRIDE];  // [n][l] bf16
  __shared__ float wrow[64];
  int bid = blockIdx.x;  // ((b*8+c)*32+h)
  int h = bid & 31, c = (bid >> 5) & 7, b = bid >> 8;
  int tid = threadIdx.x;
  int w = tid >> 6, lane = tid & 63;
  int quad = lane >> 4, lrow = lane & 15;
  int cbase = bid * CHUNKSZ;
  int rowbase = b * LSEQ + c * CHUNKSZ;
  float T = dtA_cs[cbase + CHUNKSZ - 1];
  floatx4 acc[4];
  for (int jt = 0; jt < 4; jt++) acc[jt] = (floatx4){0.f, 0.f, 0.f, 0.f};
  for (int lt = 0; lt < 4; lt++) {
    __syncthreads();
    if (tid < 64) {
      int row = rowbase + lt * 64 + tid;
      wrow[tid] = dt_sp[row * 32 + h] * __expf(T - dtA_cs[cbase + lt * 64 + tid]);
    }
    __syncthreads();
    {
      int nn = tid & 63, s4 = tid >> 6;
      for (int pass = 0; pass < 16; pass++) {
        int sr = s4 + pass * 4;
        int row = rowbase + lt * 64 + sr;
        BT[nn * ST_STRIDE + sr] = xbf[(size_t)row * CONVDIM + DINNER + nn];
        XT[nn * ST_STRIDE + sr] =
            f2bf(bf2f(xbf[(size_t)row * CONVDIM + h * DHEAD + nn]) * wrow[sr]);
      }
    }
    __syncthreads();
    for (int kk = 0; kk < 64; kk += 32) {
      shortx8 af = *(const shortx8*)&XT[(w * 16 + lrow) * ST_STRIDE + kk + quad * 8];
      for (int jt = 0; jt < 4; jt++) {
        shortx8 bf = *(const shortx8*)&BT[(jt * 16 + lrow) * ST_STRIDE + kk + quad * 8];
        acc[jt] = __builtin_amdgcn_mfma_f32_16x16x32_bf16(af, bf, acc[jt], 0, 0, 0);
      }
    }
  }
  size_t base = (size_t)bid * (DHEAD * DSTATE);
  for (int jt = 0; jt < 4; jt++) {
    int n = jt * 16 + lrow;
    for (int r = 0; r < 4; r++) {
      int p = w * 16 + quad * 4 + r;
      st_raw[base + (size_t)p * 64 + n] = acc[jt][r];
    }
  }
}

// ---------------- inter-chunk scan (in-place) ----------------
__global__ __launch_bounds__(256) void scan_k(float* __restrict__ st,
                                              const float* __restrict__ dtA_cs) {
  int bid = blockIdx.x;
  int h = bid & 31, b = bid >> 5;
  int tid = threadIdx.x;
  float s[16];
  for (int i = 0; i < 16; i++) s[i] = 0.f;
  for (int c = 0; c < NCHUNK; c++) {
    int g = (b * NCHUNK + c) * 32 + h;
    float dec = expf(dtA_cs[(size_t)g * CHUNKSZ + CHUNKSZ - 1]);
    size_t base = (size_t)g * (DHEAD * DSTATE);
    for (int i = 0; i < 16; i++) {
      int idx = tid + i * 256;
      float raw = st[base + idx];
      st[base + idx] = s[i];
      s[i] = s[i] * dec + raw;
    }
  }
}

// ---------------- MFMA ydiag: Y = (mask.decay.(C Bt)) @ Xdt + e^cs (C st^T) ----------------
#define BS_STRIDE 72
#define XT_STRIDE 68
#define PW_STRIDE 72
__global__ __launch_bounds__(256) void ydiag_mfma(const ushort* __restrict__ xbf,
                                                  const float* __restrict__ dt_sp,
                                                  const float* __restrict__ dtA_cs,
                                                  const float* __restrict__ st_in,
                                                  float* __restrict__ Y) {
  __shared__ ushort Bs[64 * BS_STRIDE];
  __shared__ ushort XsT[64 * XT_STRIDE];
  __shared__ ushort Pw[4 * 16 * PW_STRIDE];
  __shared__ float cs[256];
  int tid = threadIdx.x;
  int w = tid >> 6, lane = tid & 63;
  int quad = lane >> 4, lrow = lane & 15;
  int bid = blockIdx.x;
  int lt = bid & 3, h = (bid >> 2) & 31, c = (bid >> 7) & 7, b = bid >> 10;
  int g = (b * NCHUNK + c) * 32 + h;
  int cbase = g * CHUNKSZ;
  int rowbase = b * LSEQ + c * CHUNKSZ;

  cs[tid] = dtA_cs[cbase + tid];
  __syncthreads();

  int mrow = lt * 64 + w * 16;
  float csl[4];
  for (int r = 0; r < 4; r++) csl[r] = cs[mrow + quad * 4 + r];

  // C A-frags: direct bf16 vector loads (16B-aligned: row*4352 + 4224 + q*64 + quad*16)
  shortx8 Cf[2];
  {
    const ushort* cp = xbf + (size_t)(rowbase + mrow + lrow) * CONVDIM + DINNER + DSTATE;
    for (int q = 0; q < 2; q++)
      Cf[q] = *(const shortx8*)(cp + q * 32 + quad * 8);
  }

  floatx4 acc[4];
  for (int jt = 0; jt < 4; jt++) acc[jt] = (floatx4){0.f, 0.f, 0.f, 0.f};
  const float* stp = st_in + (size_t)g * (DHEAD * DSTATE);
  for (int q = 0; q < 2; q++) {
    for (int jt = 0; jt < 4; jt++) {
      const float* sp = stp + (size_t)(jt * 16 + lrow) * 64 + q * 32 + quad * 8;
      shortx8 sf = pack8(*(const float4*)sp, *(const float4*)(sp + 4));
      acc[jt] = __builtin_amdgcn_mfma_f32_16x16x32_bf16(Cf[q], sf, acc[jt], 0, 0, 0);
    }
  }
  for (int jt = 0; jt < 4; jt++)
    for (int r = 0; r < 4; r++) acc[jt][r] *= __expf(csl[r]);

  ushort* myP = Pw + w * 16 * PW_STRIDE;
  for (int st = 0; st <= lt; st++) {
    __syncthreads();
    {
      int nn = tid & 63, s4 = tid >> 6;
      for (int pass = 0; pass < 16; pass++) {
        int sr = s4 + pass * 4;
        int row = rowbase + st * 64 + sr;
        Bs[sr * BS_STRIDE + nn] = xbf[(size_t)row * CONVDIM + DINNER + nn];
        float dtv = dt_sp[row * 32 + h];
        XsT[nn * XT_STRIDE + sr] =
            f2bf(bf2f(xbf[(size_t)row * CONVDIM + h * DHEAD + nn]) * dtv);
      }
    }
    __syncthreads();
    for (int jt = 0; jt < 4; jt++) {
      floatx4 s = (floatx4){0.f, 0.f, 0.f, 0.f};
      for (int q = 0; q < 2; q++) {
        shortx8 bfr = *(const shortx8*)&Bs[(jt * 16 + lrow) * BS_STRIDE + q * 32 + quad * 8];
        s = __builtin_amdgcn_mfma_f32_16x16x32_bf16(Cf[q], bfr, s, 0, 0, 0);
      }
      int scol = st * 64 + jt * 16 + lrow;
      float css = cs[scol];
      for (int r = 0; r < 4; r++) {
        int l = mrow + quad * 4 + r;
        float v = (scol <= l) ? s[r] * __expf(csl[r] - css) : 0.f;
        myP[(quad * 4 + r) * PW_STRIDE + jt * 16 + lrow] = f2bf(v);
      }
    }
    shortx8 pf[2];
    for (int q = 0; q < 2; q++)
      pf[q] = *(const shortx8*)&myP[lrow * PW_STRIDE + q * 32 + quad * 8];
    for (int jt = 0; jt < 4; jt++) {
      for (int q = 0; q < 2; q++) {
        const ushort* xp = &XsT[(jt * 16 + lrow) * XT_STRIDE + q * 32 + quad * 8];
        shortx4 lo = *(const shortx4*)xp;
        shortx4 hi = *(const shortx4*)(xp + 4);
        shortx8 xf = __builtin_shufflevector(lo, hi, 0, 1, 2, 3, 4, 5, 6, 7);
        acc[jt] = __builtin_amdgcn_mfma_f32_16x16x32_bf16(pf[q], xf, acc[jt], 0, 0, 0);
      }
    }
  }
  int growb = rowbase + mrow + quad * 4;
  for (int jt = 0; jt < 4; jt++)
    for (int r = 0; r < 4; r++)
      Y[(size_t)(growb + r) * DINNER + h * DHEAD + jt * 16 + lrow] = acc[jt][r];
}

// ---------------- gated rmsnorm (+ D*X skip) -> bf16 out ----------------
__global__ __launch_bounds__(256) void gatenorm_k(const float* __restrict__ Y,
                                                  const float* __restrict__ zx,
                                                  const ushort* __restrict__ xbf,
                                                  const float* __restrict__ Dvec,
                                                  const float* __restrict__ gw,
                                                  ushort* __restrict__ ybf) {
  __shared__ float sb[4];
  int r = blockIdx.x;
  const float* yr = Y + (size_t)r * DINNER;
  const float* zr = zx + (size_t)r * DINPROJ;
  const ushort* xr = xbf + (size_t)r * CONVDIM;
  ushort* orow = ybf + (size_t)r * DINNER;
  float t[8]; float ssq = 0.f;
  for (int i = 0; i < 8; i++) {
    int cc = threadIdx.x + i * 256;
    float z = zr[cc];
    float yv = yr[cc] + Dvec[cc >> 6] * bf2f(xr[cc]);
    float gv = yv * (z / (1.f + expf(-z)));
    t[i] = gv;
    ssq += gv * gv;
  }
  float s = block_reduce_sum_256(ssq, sb);
  float sc = rsqrtf(s / (float)DINNER + EPSF);
  for (int i = 0; i < 8; i++) {
    int cc = threadIdx.x + i * 256;
    orow[cc] = f2bf(t[i] * sc * gw[cc]);
  }
}

// ---------------- launch ----------------
extern "C" void kernel_launch(void* const* d_in, const int* in_sizes, int n_in,
                              void* d_out, int out_size, void* d_ws, size_t ws_size,
                              hipStream_t stream) {
  const float* x_in     = (const float*)d_in[0];
  const float* in_w     = (const float*)d_in[1];
  const float* conv_w   = (const float*)d_in[2];
  const float* conv_b   = (const float*)d_in[3];
  const float* dt_bias  = (const float*)d_in[4];
  const float* A_log    = (const float*)d_in[5];
  const float* Dvec     = (const float*)d_in[6];
  const float* gnorm_w  = (const float*)d_in[7];
  const float* out_w    = (const float*)d_in[8];
  const float* rms_w    = (const float*)d_in[9];
  float* out = (float*)d_out;

  float* ws = (float*)d_ws;
  size_t o = 0;
  float* x_cur  = ws + o; o += (size_t)MROWS * DMODEL;
  float* zx     = ws + o; o += (size_t)MROWS * DINPROJ;
  ushort* xbf   = (ushort*)(ws + o); o += (size_t)MROWS * CONVDIM / 2;
  float* dt_sp  = ws + o; o += (size_t)MROWS * NHEADS;
  float* dtA_cs = ws + o; o += (size_t)BATCH * NCHUNK * NHEADS * CHUNKSZ;
  float* st     = ws + o; o += (size_t)BATCH * NCHUNK * NHEADS * DHEAD * DSTATE;
  float* Ybuf   = ws + o; o += (size_t)MROWS * DINNER;
  ushort* act_bf = (ushort*)(ws + o); o += (size_t)MROWS * DINNER / 2;
  ushort* w_bf   = (ushort*)(ws + o); o += (size_t)DINPROJ_PAD * DMODEL / 2;

  hipMemcpyAsync(x_cur, x_in, (size_t)MROWS * DMODEL * sizeof(float),
                 hipMemcpyDeviceToDevice, stream);

  for (int i = 0; i < 4; i++) {
    const float* in_w_i   = in_w    + (size_t)i * DINPROJ * DMODEL;
    const float* conv_w_i = conv_w  + (size_t)i * CONVDIM * DCONV;
    const float* conv_b_i = conv_b  + (size_t)i * CONVDIM;
    const float* dtb_i    = dt_bias + (size_t)i * NHEADS;
    const float* Alog_i   = A_log   + (size_t)i * NHEADS;
    const float* D_i      = Dvec    + (size_t)i * NHEADS;
    const float* gw_i     = gnorm_w + (size_t)i * DINNER;
    const float* out_w_i  = out_w   + (size_t)i * DMODEL * DINNER;
    const float* rms_w_i  = rms_w   + (size_t)i * DMODEL;

    {
      size_t ns = (size_t)DINPROJ * DMODEL, nd = (size_t)DINPROJ_PAD * DMODEL;
      cvt_bf16_k<<<(nd + 255) / 256, 256, 0, stream>>>(in_w_i, w_bf, ns, nd);
    }
    rmsnorm_k<<<MROWS, 256, 0, stream>>>(x_cur, rms_w_i, act_bf);
    gemm_nt_mfma<<<dim3(DINPROJ_PAD / 128, MROWS / 128), 256, 0, stream>>>(
        act_bf, w_bf, zx, nullptr, MROWS, DINPROJ, DMODEL);
    conv_silu_k<<<dim3((CONVDIM + 255) / 256, MROWS), 256, 0, stream>>>(
        zx, conv_w_i, conv_b_i, xbf);
    cumsum_k<<<BATCH * NCHUNK * NHEADS, 256, 0, stream>>>(zx, dtb_i, Alog_i, dt_sp, dtA_cs);
    states_mfma<<<BATCH * NCHUNK * NHEADS, 256, 0, stream>>>(xbf, dt_sp, dtA_cs, st);
    scan_k<<<BATCH * NHEADS, 256, 0, stream>>>(st, dtA_cs);
    ydiag_mfma<<<BATCH * NCHUNK * NHEADS * 4, 256, 0, stream>>>(
        xbf, dt_sp, dtA_cs, st, Ybuf);
    gatenorm_k<<<MROWS, 256, 0, stream>>>(Ybuf, zx, xbf, D_i, gw_i, act_bf);
    {
      size_t ns = (size_t)DMODEL * DINNER;
      cvt_bf16_k<<<(ns + 255) / 256, 256, 0, stream>>>(out_w_i, w_bf, ns, ns);
    }
    float* outC = (i == 3) ? out : x_cur;
    gemm_nt_mfma<<<dim3(DMODEL / 128, MROWS / 128), 256, 0, stream>>>(
        act_bf, w_bf, outC, x_cur, MROWS, DMODEL, DINNER);
  }
}

// Round 6
// 1164.999 us; speedup vs baseline: 4.5499x; 1.0323x over previous
//
#include <hip/hip_runtime.h>
#include <cmath>

#define BATCH 2
#define LSEQ 2048
#define DMODEL 1024
#define DINNER 2048
#define NHEADS 32
#define DHEAD 64
#define DSTATE 64
#define DCONV 4
#define CONVDIM (DINNER + 2*DSTATE)            // 2176
#define DINPROJ (2*DINNER + 2*DSTATE + NHEADS) // 4256
#define DINPROJ_PAD 4352                       // 34*128
#define CHUNKSZ 256
#define NCHUNK (LSEQ/CHUNKSZ)                  // 8
#define MROWS (BATCH*LSEQ)                     // 4096
#define EPSF 1e-5f

typedef __attribute__((ext_vector_type(8))) short shortx8;
typedef __attribute__((ext_vector_type(4))) short shortx4;
typedef __attribute__((ext_vector_type(4))) float floatx4;

__device__ __forceinline__ ushort f2bf(float f) {
  unsigned u = __float_as_uint(f);
  unsigned r = (u + 0x7fffu + ((u >> 16) & 1u)) >> 16;
  return (ushort)r;
}
__device__ __forceinline__ float bf2f(ushort b) {
  return __uint_as_float(((unsigned)b) << 16);
}

__device__ __forceinline__ shortx8 pack8(float4 a, float4 b) {
  shortx8 r;
  r[0] = (short)f2bf(a.x); r[1] = (short)f2bf(a.y);
  r[2] = (short)f2bf(a.z); r[3] = (short)f2bf(a.w);
  r[4] = (short)f2bf(b.x); r[5] = (short)f2bf(b.y);
  r[6] = (short)f2bf(b.z); r[7] = (short)f2bf(b.w);
  return r;
}

__device__ __forceinline__ void async_load16(const void* g, void* l) {
  __builtin_amdgcn_global_load_lds(
      (const __attribute__((address_space(1))) void*)g,
      (__attribute__((address_space(3))) void*)l, 16, 0, 0);
}

// ---------------- reductions ----------------
__device__ __forceinline__ float block_reduce_sum_256(float v, float* sb) {
  for (int off = 32; off > 0; off >>= 1) v += __shfl_down(v, off, 64);
  int lane = threadIdx.x & 63, wid = threadIdx.x >> 6;
  if (lane == 0) sb[wid] = v;
  __syncthreads();
  return sb[0] + sb[1] + sb[2] + sb[3];
}

// ---------------- fp32 -> bf16 (with zero tail padding) ----------------
__global__ __launch_bounds__(256) void cvt_bf16_k(const float* __restrict__ src,
                                                  ushort* __restrict__ dst,
                                                  size_t n_src, size_t n_dst) {
  size_t i = (size_t)blockIdx.x * 256 + threadIdx.x;
  if (i >= n_dst) return;
  float v = (i < n_src) ? src[i] : 0.f;
  dst[i] = f2bf(v);
}

// ---------------- rmsnorm (width 1024) -> bf16 out ----------------
__global__ __launch_bounds__(256) void rmsnorm_k(const float* __restrict__ x,
                                                 const float* __restrict__ w,
                                                 ushort* __restrict__ out) {
  __shared__ float sb[4];
  int r = blockIdx.x;
  const float* xr = x + (size_t)r * DMODEL;
  ushort* orow = out + (size_t)r * DMODEL;
  float v[4]; float ssq = 0.f;
  for (int i = 0; i < 4; i++) {
    v[i] = xr[threadIdx.x + i * 256];
    ssq += v[i] * v[i];
  }
  float s = block_reduce_sum_256(ssq, sb);
  float sc = rsqrtf(s / (float)DMODEL + EPSF);
  for (int i = 0; i < 4; i++) {
    int c = threadIdx.x + i * 256;
    orow[c] = f2bf(v[i] * sc * w[c]);
  }
}

// ---------------- MFMA bf16 NT GEMM (128x128 tile, BK=64, XOR-swizzled LDS) ----------------
// Output: Cbf!=nullptr -> bf16 store; else fp32 (+optional resid).
__global__ __launch_bounds__(256) void gemm_nt_mfma(const ushort* __restrict__ A,
                                                    const ushort* __restrict__ B,
                                                    float* __restrict__ C,
                                                    ushort* __restrict__ Cbf,
                                                    const float* __restrict__ resid,
                                                    int M, int N, int K) {
  __shared__ ushort Asm[128 * 64];
  __shared__ ushort Bsm[128 * 64];
  int tid = threadIdx.x;
  int wid = tid >> 6, lane = tid & 63;
  int quad = lane >> 4, lrow = lane & 15;
  int m0 = blockIdx.y * 128, n0 = blockIdx.x * 128;
  int wm = (wid >> 1) * 64, wn = (wid & 1) * 64;
  floatx4 acc[4][4];
  for (int i = 0; i < 4; i++)
    for (int j = 0; j < 4; j++) acc[i][j] = (floatx4){0.f, 0.f, 0.f, 0.f};

  for (int k0 = 0; k0 < K; k0 += 64) {
    __syncthreads();
    for (int is = 0; is < 4; is++) {
      int boff = is * 4096 + wid * 1024;        // wave-uniform LDS base
      int bb = boff + lane * 16;                // this lane's LDS byte
      int row = bb >> 7;                        // tile row (128B per row)
      int cb = bb & 127;
      int col = (cb ^ ((row & 7) << 4)) >> 1;   // swizzled source column
      async_load16(A + (size_t)(m0 + row) * K + k0 + col, (char*)Asm + boff);
      async_load16(B + (size_t)(n0 + row) * K + k0 + col, (char*)Bsm + boff);
    }
    __syncthreads();
    for (int kk = 0; kk < 64; kk += 32) {
      shortx8 af[4], bf[4];
      for (int i = 0; i < 4; i++) {
        int r = wm + i * 16 + lrow;
        int cbyte = ((kk + quad * 8) * 2) ^ ((r & 7) << 4);
        af[i] = *(const shortx8*)((const char*)Asm + r * 128 + cbyte);
      }
      for (int j = 0; j < 4; j++) {
        int r = wn + j * 16 + lrow;
        int cbyte = ((kk + quad * 8) * 2) ^ ((r & 7) << 4);
        bf[j] = *(const shortx8*)((const char*)Bsm + r * 128 + cbyte);
      }
      for (int i = 0; i < 4; i++)
        for (int j = 0; j < 4; j++)
          acc[i][j] = __builtin_amdgcn_mfma_f32_16x16x32_bf16(af[i], bf[j], acc[i][j], 0, 0, 0);
    }
  }
  if (Cbf) {
    for (int i = 0; i < 4; i++) {
      int r0 = m0 + wm + i * 16 + quad * 4;
      for (int j = 0; j < 4; j++) {
        int n = n0 + wn + j * 16 + lrow;
        if (n < N)
          for (int r = 0; r < 4; r++)
            Cbf[(size_t)(r0 + r) * N + n] = f2bf(acc[i][j][r]);
      }
    }
  } else {
    bool hasR = (resid != nullptr);
    for (int i = 0; i < 4; i++) {
      int r0 = m0 + wm + i * 16 + quad * 4;
      for (int j = 0; j < 4; j++) {
        int n = n0 + wn + j * 16 + lrow;
        if (n < N) {
          for (int r = 0; r < 4; r++) {
            size_t idx = (size_t)(r0 + r) * N + n;
            float v = acc[i][j][r];
            if (hasR) v += resid[idx];
            C[idx] = v;
          }
        }
      }
    }
  }
}

// ---------------- depthwise conv + silu -> bf16 xBC ----------------
__global__ __launch_bounds__(256) void conv_silu_k(const ushort* __restrict__ zxbf,
                                                   const float* __restrict__ cw,
                                                   const float* __restrict__ cb,
                                                   ushort* __restrict__ xbf) {
  int ch = blockIdx.x * 256 + threadIdx.x;
  if (ch >= CONVDIM) return;
  int r = blockIdx.y;
  int b = r >> 11, l = r & (LSEQ - 1);
  float acc = cb[ch];
  for (int k = 0; k < DCONV; k++) {
    int ls = l - (DCONV - 1) + k;
    if (ls >= 0)
      acc += bf2f(zxbf[(size_t)(b * LSEQ + ls) * DINPROJ + DINNER + ch]) * cw[ch * DCONV + k];
  }
  float s = acc / (1.f + expf(-acc));
  xbf[(size_t)r * CONVDIM + ch] = f2bf(s);
}

// ---------------- fused dt softplus + per-chunk inclusive cumsum of dt*A ----------------
__global__ __launch_bounds__(256) void cumsum_k(const ushort* __restrict__ zxbf,
                                                const float* __restrict__ dt_bias,
                                                const float* __restrict__ A_log,
                                                float* __restrict__ dt_sp,
                                                float* __restrict__ dtA_cs) {
  __shared__ float buf[256];
  int bid = blockIdx.x;  // ((b*8+c)*32+h)
  int h = bid & 31, c = (bid >> 5) & 7, b = bid >> 8;
  int l = threadIdx.x;
  float Aneg = -expf(A_log[h]);
  int row = b * LSEQ + c * CHUNKSZ + l;
  float v = bf2f(zxbf[(size_t)row * DINPROJ + DINNER + CONVDIM + h]) + dt_bias[h];
  float dtv = (v > 20.f) ? v : log1pf(expf(v));
  dt_sp[row * 32 + h] = dtv;
  buf[l] = dtv * Aneg;
  __syncthreads();
  for (int off = 1; off < 256; off <<= 1) {
    float add = (l >= off) ? buf[l - off] : 0.f;
    __syncthreads();
    buf[l] += add;
    __syncthreads();
  }
  dtA_cs[(size_t)bid * CHUNKSZ + l] = buf[l];
}

// ---------------- MFMA per-chunk end states: st[p][n] = sum_l (Xdt*decay)[l,p] B[l,n] ----------------
#define ST_STRIDE 72
__global__ __launch_bounds__(256) void states_mfma(const ushort* __restrict__ xbf,
                                                   const float* __restrict__ dt_sp,
                                                   const float* __restrict__ dtA_cs,
                                                   float* __restrict__ st_raw) {
  __shared__ ushort XT[64 * ST_STRIDE];  // [p][l] bf16
  __shared__ ushort BT[64 * ST_STRIDE];  // [n][l] bf16
  __shared__ float wrow[64];
  int bid = blockIdx.x;  // ((b*8+c)*32+h)
  int h = bid & 31, c = (bid >> 5) & 7, b = bid >> 8;
  int tid = threadIdx.x;
  int w = tid >> 6, lane = tid & 63;
  int quad = lane >> 4, lrow = lane & 15;
  int cbase = bid * CHUNKSZ;
  int rowbase = b * LSEQ + c * CHUNKSZ;
  float T = dtA_cs[cbase + CHUNKSZ - 1];
  floatx4 acc[4];
  for (int jt = 0; jt < 4; jt++) acc[jt] = (floatx4){0.f, 0.f, 0.f, 0.f};
  int half = tid & 31, srb = tid >> 5;
  for (int lt = 0; lt < 4; lt++) {
    __syncthreads();
    if (tid < 64) {
      int row = rowbase + lt * 64 + tid;
      wrow[tid] = dt_sp[row * 32 + h] * __expf(T - dtA_cs[cbase + lt * 64 + tid]);
    }
    __syncthreads();
    for (int pass = 0; pass < 8; pass++) {
      int sr = srb + pass * 8;
      int row = rowbase + lt * 64 + sr;
      uint bv = *(const uint*)(xbf + (size_t)row * CONVDIM + DINNER + 2 * half);
      uint xv = *(const uint*)(xbf + (size_t)row * CONVDIM + h * DHEAD + 2 * half);
      float wv = wrow[sr];
      BT[(2 * half) * ST_STRIDE + sr]     = (ushort)(bv & 0xffff);
      BT[(2 * half + 1) * ST_STRIDE + sr] = (ushort)(bv >> 16);
      XT[(2 * half) * ST_STRIDE + sr]     = f2bf(bf2f((ushort)(xv & 0xffff)) * wv);
      XT[(2 * half + 1) * ST_STRIDE + sr] = f2bf(bf2f((ushort)(xv >> 16)) * wv);
    }
    __syncthreads();
    for (int kk = 0; kk < 64; kk += 32) {
      shortx8 af = *(const shortx8*)&XT[(w * 16 + lrow) * ST_STRIDE + kk + quad * 8];
      for (int jt = 0; jt < 4; jt++) {
        shortx8 bf = *(const shortx8*)&BT[(jt * 16 + lrow) * ST_STRIDE + kk + quad * 8];
        acc[jt] = __builtin_amdgcn_mfma_f32_16x16x32_bf16(af, bf, acc[jt], 0, 0, 0);
      }
    }
  }
  size_t base = (size_t)bid * (DHEAD * DSTATE);
  for (int jt = 0; jt < 4; jt++) {
    int n = jt * 16 + lrow;
    for (int r = 0; r < 4; r++) {
      int p = w * 16 + quad * 4 + r;
      st_raw[base + (size_t)p * 64 + n] = acc[jt][r];
    }
  }
}

// ---------------- inter-chunk scan (in-place) ----------------
__global__ __launch_bounds__(256) void scan_k(float* __restrict__ st,
                                              const float* __restrict__ dtA_cs) {
  int bid = blockIdx.x;
  int h = bid & 31, b = bid >> 5;
  int tid = threadIdx.x;
  float s[16];
  for (int i = 0; i < 16; i++) s[i] = 0.f;
  for (int c = 0; c < NCHUNK; c++) {
    int g = (b * NCHUNK + c) * 32 + h;
    float dec = expf(dtA_cs[(size_t)g * CHUNKSZ + CHUNKSZ - 1]);
    size_t base = (size_t)g * (DHEAD * DSTATE);
    for (int i = 0; i < 16; i++) {
      int idx = tid + i * 256;
      float raw = st[base + idx];
      st[base + idx] = s[i];
      s[i] = s[i] * dec + raw;
    }
  }
}

// ---------------- MFMA ydiag: Y = (mask.decay.(C Bt)) @ Xdt + e^cs (C st^T) -> bf16 Y ----------------
#define BS_STRIDE 72
#define XT_STRIDE 68
#define PW_STRIDE 72
__global__ __launch_bounds__(256) void ydiag_mfma(const ushort* __restrict__ xbf,
                                                  const float* __restrict__ dt_sp,
                                                  const float* __restrict__ dtA_cs,
                                                  const float* __restrict__ st_in,
                                                  ushort* __restrict__ Y) {
  __shared__ ushort Bs[64 * BS_STRIDE];
  __shared__ ushort XsT[64 * XT_STRIDE];
  __shared__ ushort Pw[4 * 16 * PW_STRIDE];
  __shared__ float cs[256];
  int tid = threadIdx.x;
  int w = tid >> 6, lane = tid & 63;
  int quad = lane >> 4, lrow = lane & 15;
  int bid = blockIdx.x;
  int lt = bid & 3, h = (bid >> 2) & 31, c = (bid >> 7) & 7, b = bid >> 10;
  int g = (b * NCHUNK + c) * 32 + h;
  int cbase = g * CHUNKSZ;
  int rowbase = b * LSEQ + c * CHUNKSZ;

  cs[tid] = dtA_cs[cbase + tid];
  __syncthreads();

  int mrow = lt * 64 + w * 16;
  float csl[4];
  for (int r = 0; r < 4; r++) csl[r] = cs[mrow + quad * 4 + r];

  shortx8 Cf[2];
  {
    const ushort* cp = xbf + (size_t)(rowbase + mrow + lrow) * CONVDIM + DINNER + DSTATE;
    for (int q = 0; q < 2; q++)
      Cf[q] = *(const shortx8*)(cp + q * 32 + quad * 8);
  }

  floatx4 acc[4];
  for (int jt = 0; jt < 4; jt++) acc[jt] = (floatx4){0.f, 0.f, 0.f, 0.f};
  const float* stp = st_in + (size_t)g * (DHEAD * DSTATE);
  for (int q = 0; q < 2; q++) {
    for (int jt = 0; jt < 4; jt++) {
      const float* sp = stp + (size_t)(jt * 16 + lrow) * 64 + q * 32 + quad * 8;
      shortx8 sf = pack8(*(const float4*)sp, *(const float4*)(sp + 4));
      acc[jt] = __builtin_amdgcn_mfma_f32_16x16x32_bf16(Cf[q], sf, acc[jt], 0, 0, 0);
    }
  }
  for (int jt = 0; jt < 4; jt++)
    for (int r = 0; r < 4; r++) acc[jt][r] *= __expf(csl[r]);

  ushort* myP = Pw + w * 16 * PW_STRIDE;
  int half = tid & 31, srb = tid >> 5;
  for (int st = 0; st <= lt; st++) {
    __syncthreads();
    for (int pass = 0; pass < 8; pass++) {
      int sr = srb + pass * 8;
      int row = rowbase + st * 64 + sr;
      uint bv = *(const uint*)(xbf + (size_t)row * CONVDIM + DINNER + 2 * half);
      *(uint*)&Bs[sr * BS_STRIDE + 2 * half] = bv;
      float dtv = dt_sp[row * 32 + h];
      uint xv = *(const uint*)(xbf + (size_t)row * CONVDIM + h * DHEAD + 2 * half);
      XsT[(2 * half) * XT_STRIDE + sr]     = f2bf(bf2f((ushort)(xv & 0xffff)) * dtv);
      XsT[(2 * half + 1) * XT_STRIDE + sr] = f2bf(bf2f((ushort)(xv >> 16)) * dtv);
    }
    __syncthreads();
    for (int jt = 0; jt < 4; jt++) {
      floatx4 s = (floatx4){0.f, 0.f, 0.f, 0.f};
      for (int q = 0; q < 2; q++) {
        shortx8 bfr = *(const shortx8*)&Bs[(jt * 16 + lrow) * BS_STRIDE + q * 32 + quad * 8];
        s = __builtin_amdgcn_mfma_f32_16x16x32_bf16(Cf[q], bfr, s, 0, 0, 0);
      }
      int scol = st * 64 + jt * 16 + lrow;
      float css = cs[scol];
      for (int r = 0; r < 4; r++) {
        int l = mrow + quad * 4 + r;
        float v = (scol <= l) ? s[r] * __expf(csl[r] - css) : 0.f;
        myP[(quad * 4 + r) * PW_STRIDE + jt * 16 + lrow] = f2bf(v);
      }
    }
    shortx8 pf[2];
    for (int q = 0; q < 2; q++)
      pf[q] = *(const shortx8*)&myP[lrow * PW_STRIDE + q * 32 + quad * 8];
    for (int jt = 0; jt < 4; jt++) {
      for (int q = 0; q < 2; q++) {
        const ushort* xp = &XsT[(jt * 16 + lrow) * XT_STRIDE + q * 32 + quad * 8];
        shortx4 lo = *(const shortx4*)xp;
        shortx4 hi = *(const shortx4*)(xp + 4);
        shortx8 xf = __builtin_shufflevector(lo, hi, 0, 1, 2, 3, 4, 5, 6, 7);
        acc[jt] = __builtin_amdgcn_mfma_f32_16x16x32_bf16(pf[q], xf, acc[jt], 0, 0, 0);
      }
    }
  }
  int growb = rowbase + mrow + quad * 4;
  for (int jt = 0; jt < 4; jt++)
    for (int r = 0; r < 4; r++)
      Y[(size_t)(growb + r) * DINNER + h * DHEAD + jt * 16 + lrow] = f2bf(acc[jt][r]);
}

// ---------------- gated rmsnorm (+ D*X skip) -> bf16 out ----------------
__global__ __launch_bounds__(256) void gatenorm_k(const ushort* __restrict__ Ybf,
                                                  const ushort* __restrict__ zxbf,
                                                  const ushort* __restrict__ xbf,
                                                  const float* __restrict__ Dvec,
                                                  const float* __restrict__ gw,
                                                  ushort* __restrict__ obf) {
  __shared__ float sb[4];
  int r = blockIdx.x;
  const ushort* yr = Ybf + (size_t)r * DINNER;
  const ushort* zr = zxbf + (size_t)r * DINPROJ;
  const ushort* xr = xbf + (size_t)r * CONVDIM;
  ushort* orow = obf + (size_t)r * DINNER;
  float t[8]; float ssq = 0.f;
  for (int i = 0; i < 8; i++) {
    int cc = threadIdx.x + i * 256;
    float z = bf2f(zr[cc]);
    float yv = bf2f(yr[cc]) + Dvec[cc >> 6] * bf2f(xr[cc]);
    float gv = yv * (z / (1.f + expf(-z)));
    t[i] = gv;
    ssq += gv * gv;
  }
  float s = block_reduce_sum_256(ssq, sb);
  float sc = rsqrtf(s / (float)DINNER + EPSF);
  for (int i = 0; i < 8; i++) {
    int cc = threadIdx.x + i * 256;
    orow[cc] = f2bf(t[i] * sc * gw[cc]);
  }
}

// ---------------- launch ----------------
extern "C" void kernel_launch(void* const* d_in, const int* in_sizes, int n_in,
                              void* d_out, int out_size, void* d_ws, size_t ws_size,
                              hipStream_t stream) {
  const float* x_in     = (const float*)d_in[0];
  const float* in_w     = (const float*)d_in[1];
  const float* conv_w   = (const float*)d_in[2];
  const float* conv_b   = (const float*)d_in[3];
  const float* dt_bias  = (const float*)d_in[4];
  const float* A_log    = (const float*)d_in[5];
  const float* Dvec     = (const float*)d_in[6];
  const float* gnorm_w  = (const float*)d_in[7];
  const float* out_w    = (const float*)d_in[8];
  const float* rms_w    = (const float*)d_in[9];
  float* out = (float*)d_out;

  float* ws = (float*)d_ws;
  size_t o = 0;
  float* x_cur  = ws + o; o += (size_t)MROWS * DMODEL;                       // 16.8 MB
  ushort* zx_bf = (ushort*)(ws + o); o += (size_t)MROWS * DINPROJ / 2;       // 34.9 MB
  ushort* xbf   = (ushort*)(ws + o); o += (size_t)MROWS * CONVDIM / 2;       // 17.8 MB
  float* dt_sp  = ws + o; o += (size_t)MROWS * NHEADS;                       // 0.5 MB
  float* dtA_cs = ws + o; o += (size_t)BATCH * NCHUNK * NHEADS * CHUNKSZ;    // 0.5 MB
  float* st     = ws + o; o += (size_t)BATCH * NCHUNK * NHEADS * DHEAD * DSTATE;  // 8.4 MB
  ushort* Ybf   = (ushort*)(ws + o); o += (size_t)MROWS * DINNER / 2;        // 16.8 MB
  ushort* act_bf = (ushort*)(ws + o); o += (size_t)MROWS * DINNER / 2;       // 16.8 MB
  ushort* w_bf   = (ushort*)(ws + o); o += (size_t)DINPROJ_PAD * DMODEL / 2; // 8.9 MB

  hipMemcpyAsync(x_cur, x_in, (size_t)MROWS * DMODEL * sizeof(float),
                 hipMemcpyDeviceToDevice, stream);

  for (int i = 0; i < 4; i++) {
    const float* in_w_i   = in_w    + (size_t)i * DINPROJ * DMODEL;
    const float* conv_w_i = conv_w  + (size_t)i * CONVDIM * DCONV;
    const float* conv_b_i = conv_b  + (size_t)i * CONVDIM;
    const float* dtb_i    = dt_bias + (size_t)i * NHEADS;
    const float* Alog_i   = A_log   + (size_t)i * NHEADS;
    const float* D_i      = Dvec    + (size_t)i * NHEADS;
    const float* gw_i     = gnorm_w + (size_t)i * DINNER;
    const float* out_w_i  = out_w   + (size_t)i * DMODEL * DINNER;
    const float* rms_w_i  = rms_w   + (size_t)i * DMODEL;

    {
      size_t ns = (size_t)DINPROJ * DMODEL, nd = (size_t)DINPROJ_PAD * DMODEL;
      cvt_bf16_k<<<(nd + 255) / 256, 256, 0, stream>>>(in_w_i, w_bf, ns, nd);
    }
    rmsnorm_k<<<MROWS, 256, 0, stream>>>(x_cur, rms_w_i, act_bf);
    gemm_nt_mfma<<<dim3(DINPROJ_PAD / 128, MROWS / 128), 256, 0, stream>>>(
        act_bf, w_bf, nullptr, zx_bf, nullptr, MROWS, DINPROJ, DMODEL);
    conv_silu_k<<<dim3((CONVDIM + 255) / 256, MROWS), 256, 0, stream>>>(
        zx_bf, conv_w_i, conv_b_i, xbf);
    cumsum_k<<<BATCH * NCHUNK * NHEADS, 256, 0, stream>>>(zx_bf, dtb_i, Alog_i, dt_sp, dtA_cs);
    states_mfma<<<BATCH * NCHUNK * NHEADS, 256, 0, stream>>>(xbf, dt_sp, dtA_cs, st);
    scan_k<<<BATCH * NHEADS, 256, 0, stream>>>(st, dtA_cs);
    ydiag_mfma<<<BATCH * NCHUNK * NHEADS * 4, 256, 0, stream>>>(
        xbf, dt_sp, dtA_cs, st, Ybf);
    gatenorm_k<<<MROWS, 256, 0, stream>>>(Ybf, zx_bf, xbf, D_i, gw_i, act_bf);
    {
      size_t ns = (size_t)DMODEL * DINNER;
      cvt_bf16_k<<<(ns + 255) / 256, 256, 0, stream>>>(out_w_i, w_bf, ns, ns);
    }
    float* outC = (i == 3) ? out : x_cur;
    gemm_nt_mfma<<<dim3(DMODEL / 128, MROWS / 128), 256, 0, stream>>>(
        act_bf, w_bf, outC, nullptr, x_cur, MROWS, DMODEL, DINNER);
  }
}